// Round 1
// baseline (1115.674 us; speedup 1.0000x reference)
//
#include <hip/hip_runtime.h>
#include <hip/hip_bf16.h>

// Problem constants (match reference)
#define NN 100000      // nodes
#define NE 500000      // edges
#define DD 128         // h_dim
#define RR 230         // relation types
#define LL 2           // layers
// F.rrelu eval-mode slope = (1/8 + 1/3)/2
#define SLOPE 0.2291666666666666667f

// ---------------------------------------------------------------------------
// h0[n, :] = ent_embeds[node_id[n], :]   (float4-vectorized gather)
// ---------------------------------------------------------------------------
__global__ __launch_bounds__(256) void gather_k(const float* __restrict__ ent,
                                                const int* __restrict__ node_id,
                                                float* __restrict__ h) {
    int i = blockIdx.x * blockDim.x + threadIdx.x;   // float4 index
    if (i >= NN * (DD / 4)) return;
    int n = i >> 5;        // / (DD/4 = 32)
    int c = i & 31;
    const float4* srcp = (const float4*)(ent + (size_t)node_id[n] * DD);
    ((float4*)h)[i] = srcp[c];
}

// ---------------------------------------------------------------------------
// Per-edge basis-block message + atomic scatter-add into agg[dst].
// One wave (64 lanes) per edge; lane b owns basis block b (2 in, 2 out).
// weight layout per edge: w[b][i][o] at t*256 + b*4 + i*2 + o
// ---------------------------------------------------------------------------
__global__ __launch_bounds__(256) void edge_k(const float* __restrict__ h,
                                              const float* __restrict__ wl,   // weight for this layer [R,256]
                                              const int* __restrict__ et,
                                              const int* __restrict__ src,
                                              const int* __restrict__ dst,
                                              float* __restrict__ agg) {
    int gid  = blockIdx.x * blockDim.x + threadIdx.x;
    int e    = gid >> 6;
    int lane = threadIdx.x & 63;
    if (e >= NE) return;
    int s = src[e];
    int d = dst[e];
    int t = et[e];
    float2 x = *(const float2*)(h + (size_t)s * DD + lane * 2);
    float4 w = *(const float4*)(wl + (size_t)t * 256 + lane * 4);
    // m_o = x0*w[i=0][o] + x1*w[i=1][o];  w = (w00, w01, w10, w11)
    float m0 = fmaf(x.x, w.x, x.y * w.z);
    float m1 = fmaf(x.x, w.y, x.y * w.w);
    float* ap = agg + (size_t)d * DD + lane * 2;
    unsafeAtomicAdd(ap,     m0);
    unsafeAtomicAdd(ap + 1, m1);
}

// ---------------------------------------------------------------------------
// out[n,:] = rrelu( agg[n,:]*norm[n] + h[n,:] @ W )
// W (128x128 f32, 64KB) staged in LDS. One wave handles 8 rows;
// lane owns 2 output columns -> 16 FMA per k-step per wave-lane.
// ---------------------------------------------------------------------------
__global__ __launch_bounds__(256) void apply_k(const float* __restrict__ agg,
                                               const float* __restrict__ h,
                                               const float* __restrict__ W,    // loop_weight for this layer
                                               const float* __restrict__ norm,
                                               float* __restrict__ out) {
    __shared__ float Wl[DD * DD];
    {
        const float4* Ws = (const float4*)W;
        float4*       Wd = (float4*)Wl;
        for (int i = threadIdx.x; i < DD * DD / 4; i += 256) Wd[i] = Ws[i];
    }
    __syncthreads();

    int lane = threadIdx.x & 63;
    int wid  = threadIdx.x >> 6;
    long n0  = ((long)blockIdx.x * 4 + wid) * 8;   // 8 rows per wave
    if (n0 >= NN) return;

    float acc[8][2];
    #pragma unroll
    for (int r = 0; r < 8; ++r) { acc[r][0] = 0.f; acc[r][1] = 0.f; }

    const float* hp = h + n0 * DD;
    #pragma unroll 4
    for (int k = 0; k < DD; ++k) {
        float2 w2 = *(const float2*)(&Wl[k * DD + lane * 2]);
        #pragma unroll
        for (int r = 0; r < 8; ++r) {
            float hv = hp[r * DD + k];      // wave-uniform broadcast, L1-hit
            acc[r][0] = fmaf(hv, w2.x, acc[r][0]);
            acc[r][1] = fmaf(hv, w2.y, acc[r][1]);
        }
    }

    #pragma unroll
    for (int r = 0; r < 8; ++r) {
        long n = n0 + r;
        float nv = norm[n];
        float a0 = fmaf(agg[n * DD + lane * 2],     nv, acc[r][0]);
        float a1 = fmaf(agg[n * DD + lane * 2 + 1], nv, acc[r][1]);
        a0 = (a0 >= 0.f) ? a0 : a0 * SLOPE;
        a1 = (a1 >= 0.f) ? a1 : a1 * SLOPE;
        *(float2*)(out + n * DD + lane * 2) = make_float2(a0, a1);
    }
}

extern "C" void kernel_launch(void* const* d_in, const int* in_sizes, int n_in,
                              void* d_out, int out_size, void* d_ws, size_t ws_size,
                              hipStream_t stream) {
    const float* ent_embeds  = (const float*)d_in[0];
    // d_in[1] = rel_embeds (unused by the layer)
    const float* weight      = (const float*)d_in[2];   // [L, R, 256]
    const float* loop_weight = (const float*)d_in[3];   // [L, 128, 128]
    const float* norm        = (const float*)d_in[4];   // [N, 1]
    const int*   node_id     = (const int*)d_in[5];
    const int*   edge_type   = (const int*)d_in[6];
    const int*   src         = (const int*)d_in[7];
    const int*   dst         = (const int*)d_in[8];
    float*       out         = (float*)d_out;

    float* bufA = (float*)d_ws;                 // h_cur  (N*D f32)
    float* bufB = bufA + (size_t)NN * DD;       // agg    (N*D f32)

    // h0 = ent_embeds[node_id]
    gather_k<<<(NN * (DD / 4) + 255) / 256, 256, 0, stream>>>(ent_embeds, node_id, bufA);

    const int edge_blocks = (NE * 64) / 256;    // 1 wave per edge

    // ---- layer 0: h in bufA, agg in bufB, h1 written in-place into bufB ----
    hipMemsetAsync(bufB, 0, (size_t)NN * DD * sizeof(float), stream);
    edge_k<<<edge_blocks, 256, 0, stream>>>(bufA, weight, edge_type, src, dst, bufB);
    apply_k<<<NN / 32, 256, 0, stream>>>(bufB, bufA, loop_weight, norm, bufB);

    // ---- layer 1: h in bufB, agg in bufA, result -> d_out ----
    hipMemsetAsync(bufA, 0, (size_t)NN * DD * sizeof(float), stream);
    edge_k<<<edge_blocks, 256, 0, stream>>>(bufB, weight + (size_t)RR * 256, edge_type, src, dst, bufA);
    apply_k<<<NN / 32, 256, 0, stream>>>(bufA, bufB, loop_weight + (size_t)DD * DD, norm, out);
}

// Round 2
// 470.620 us; speedup vs baseline: 2.3706x; 2.3706x over previous
//
#include <hip/hip_runtime.h>
#include <hip/hip_bf16.h>

// Problem constants (match reference)
#define NN 100000      // nodes
#define NE 500000      // edges
#define DD 128         // h_dim
#define RR 230         // relation types
// F.rrelu eval-mode slope = (1/8 + 1/3)/2
#define SLOPE 0.2291666666666666667f

// ===========================================================================
// CSR-by-dst build: histogram -> 2-level exclusive scan -> scatter
// epack[pos] = (src << 8) | type   (src < 2^17, type < 230 -> fits 25 bits)
// ===========================================================================
__global__ __launch_bounds__(256) void hist_k(const int* __restrict__ dst,
                                              int* __restrict__ cnt) {
    int e = blockIdx.x * 256 + threadIdx.x;
    if (e >= NE) return;
    atomicAdd(&cnt[dst[e]], 1);
}

__global__ __launch_bounds__(256) void scan1_k(const int* __restrict__ cnt,
                                               int* __restrict__ off,
                                               int* __restrict__ bsum) {
    __shared__ int sh[256];
    int i = blockIdx.x * 256 + threadIdx.x;
    int v = (i < NN) ? cnt[i] : 0;
    sh[threadIdx.x] = v;
    __syncthreads();
    for (int d = 1; d < 256; d <<= 1) {
        int t = (threadIdx.x >= d) ? sh[threadIdx.x - d] : 0;
        __syncthreads();
        sh[threadIdx.x] += t;
        __syncthreads();
    }
    if (i < NN) off[i] = sh[threadIdx.x] - v;          // exclusive
    if (threadIdx.x == 255) bsum[blockIdx.x] = sh[255];
}

__global__ __launch_bounds__(512) void scan2_k(int* __restrict__ bsum, int nb) {
    __shared__ int sh[512];
    int v = (threadIdx.x < nb) ? bsum[threadIdx.x] : 0;
    sh[threadIdx.x] = v;
    __syncthreads();
    for (int d = 1; d < 512; d <<= 1) {
        int t = (threadIdx.x >= d) ? sh[threadIdx.x - d] : 0;
        __syncthreads();
        sh[threadIdx.x] += t;
        __syncthreads();
    }
    if (threadIdx.x < nb) bsum[threadIdx.x] = sh[threadIdx.x] - v;  // exclusive
}

__global__ __launch_bounds__(256) void scan3_k(int* __restrict__ off,
                                               const int* __restrict__ bsum,
                                               int* __restrict__ cursor) {
    int i = blockIdx.x * 256 + threadIdx.x;
    if (i < NN) {
        int o = off[i] + bsum[blockIdx.x];
        off[i] = o;
        cursor[i] = o;
    }
    if (i == 0) off[NN] = NE;
}

__global__ __launch_bounds__(256) void scat_k(const int* __restrict__ src,
                                              const int* __restrict__ et,
                                              const int* __restrict__ dst,
                                              int* __restrict__ cursor,
                                              int* __restrict__ epack) {
    int e = blockIdx.x * 256 + threadIdx.x;
    if (e >= NE) return;
    int pos = atomicAdd(&cursor[dst[e]], 1);
    epack[pos] = (src[e] << 8) | et[e];
}

// ===========================================================================
// Aggregate: one wave per dst node, no atomics. Lane b owns basis block b.
// agg[n,:] = norm[n] * sum_{e in CSR[n]} blockdiag_msg(h[src_e], w[type_e])
// IND: h row index goes through node_id (layer 0 reads ent_embeds directly).
// ===========================================================================
template<bool IND>
__global__ __launch_bounds__(256) void agg_k(const float* __restrict__ h,
                                             const int* __restrict__ nid,
                                             const int* __restrict__ off,
                                             const int* __restrict__ epack,
                                             const float* __restrict__ wl,   // [R,256] this layer
                                             const float* __restrict__ norm,
                                             float* __restrict__ agg) {
    int w    = (blockIdx.x * 256 + threadIdx.x) >> 6;
    int lane = threadIdx.x & 63;
    if (w >= NN) return;
    int e0 = off[w], e1 = off[w + 1];
    float a0 = 0.f, a1 = 0.f;
    for (int e = e0; e < e1; ++e) {
        int p = epack[e];                 // wave-uniform broadcast load
        int s = p >> 8;
        int t = p & 255;
        int row = IND ? nid[s] : s;
        float2 x = *(const float2*)(h + (size_t)row * DD + lane * 2);
        float4 wv = *(const float4*)(wl + (size_t)t * 256 + lane * 4);
        a0 = fmaf(x.x, wv.x, fmaf(x.y, wv.z, a0));
        a1 = fmaf(x.x, wv.y, fmaf(x.y, wv.w, a1));
    }
    float nv = norm[w];
    *(float2*)(agg + (size_t)w * DD + lane * 2) = make_float2(a0 * nv, a1 * nv);
}

// ===========================================================================
// out[n,:] = rrelu( agg[n,:] + h[n,:] @ W )   (norm already folded into agg)
// W (128x128 f32, 64KB) in LDS. One wave per 8 rows, lane owns 2 columns.
// Safe in-place on h==out: each wave reads only the 8 rows it later writes.
// ===========================================================================
template<bool IND>
__global__ __launch_bounds__(256) void apply_k(const float* __restrict__ agg,
                                               const float* __restrict__ h,
                                               const int* __restrict__ nid,
                                               const float* __restrict__ W,
                                               float* __restrict__ out) {
    __shared__ float Wl[DD * DD];
    {
        const float4* Ws = (const float4*)W;
        float4*       Wd = (float4*)Wl;
        for (int i = threadIdx.x; i < DD * DD / 4; i += 256) Wd[i] = Ws[i];
    }
    __syncthreads();

    int lane = threadIdx.x & 63;
    int wid  = threadIdx.x >> 6;
    long n0  = ((long)blockIdx.x * 4 + wid) * 8;   // 8 rows per wave
    if (n0 >= NN) return;

    const float* hp[8];
    #pragma unroll
    for (int r = 0; r < 8; ++r) {
        long n = n0 + r;
        hp[r] = h + (size_t)(IND ? nid[n] : (int)n) * DD;
    }

    float acc[8][2];
    #pragma unroll
    for (int r = 0; r < 8; ++r) { acc[r][0] = 0.f; acc[r][1] = 0.f; }

    #pragma unroll 4
    for (int k = 0; k < DD; ++k) {
        float2 w2 = *(const float2*)(&Wl[k * DD + lane * 2]);
        #pragma unroll
        for (int r = 0; r < 8; ++r) {
            float hv = hp[r][k];            // wave-uniform broadcast, cache-hit
            acc[r][0] = fmaf(hv, w2.x, acc[r][0]);
            acc[r][1] = fmaf(hv, w2.y, acc[r][1]);
        }
    }

    #pragma unroll
    for (int r = 0; r < 8; ++r) {
        long n = n0 + r;
        float a0 = agg[n * DD + lane * 2]     + acc[r][0];
        float a1 = agg[n * DD + lane * 2 + 1] + acc[r][1];
        a0 = (a0 >= 0.f) ? a0 : a0 * SLOPE;
        a1 = (a1 >= 0.f) ? a1 : a1 * SLOPE;
        *(float2*)(out + n * DD + lane * 2) = make_float2(a0, a1);
    }
}

extern "C" void kernel_launch(void* const* d_in, const int* in_sizes, int n_in,
                              void* d_out, int out_size, void* d_ws, size_t ws_size,
                              hipStream_t stream) {
    const float* ent_embeds  = (const float*)d_in[0];
    // d_in[1] = rel_embeds (unused by the layer)
    const float* weight      = (const float*)d_in[2];   // [L, R, 256]
    const float* loop_weight = (const float*)d_in[3];   // [L, 128, 128]
    const float* norm        = (const float*)d_in[4];   // [N, 1]
    const int*   node_id     = (const int*)d_in[5];
    const int*   edge_type   = (const int*)d_in[6];
    const int*   src         = (const int*)d_in[7];
    const int*   dst         = (const int*)d_in[8];
    float*       out         = (float*)d_out;

    // Workspace layout (~54.5 MB total; 102.4 MB proven available in R1)
    float* aggbuf = (float*)d_ws;                               // N*D f32 = 51.2 MB
    int*   cnt    = (int*)(aggbuf + (size_t)NN * DD);           // NN
    int*   off    = cnt + NN;                                   // NN+1
    int*   cursor = off + NN + 1;                               // NN
    int*   bsum   = cursor + NN;                                // 512
    int*   epack  = bsum + 512;                                 // NE

    const int NB_E = (NE + 255) / 256;     // 1954
    const int NB_N = (NN + 255) / 256;     // 391

    // ---- CSR build (once; shared by both layers) ----
    hipMemsetAsync(cnt, 0, (size_t)NN * sizeof(int), stream);
    hist_k <<<NB_E, 256, 0, stream>>>(dst, cnt);
    scan1_k<<<NB_N, 256, 0, stream>>>(cnt, off, bsum);
    scan2_k<<<1,    512, 0, stream>>>(bsum, NB_N);
    scan3_k<<<NB_N, 256, 0, stream>>>(off, bsum, cursor);
    scat_k <<<NB_E, 256, 0, stream>>>(src, edge_type, dst, cursor, epack);

    const int AGG_BLOCKS = (NN * 64) / 256;   // 25000, one wave per node
    const int APL_BLOCKS = NN / 32;           // 3125, 8 rows per wave

    // ---- layer 0: h0 = ent_embeds[node_id] via double indirection ----
    agg_k<true>  <<<AGG_BLOCKS, 256, 0, stream>>>(ent_embeds, node_id, off, epack,
                                                  weight, norm, aggbuf);
    apply_k<true><<<APL_BLOCKS, 256, 0, stream>>>(aggbuf, ent_embeds, node_id,
                                                  loop_weight, out);

    // ---- layer 1: h1 lives in d_out; apply runs safely in-place ----
    agg_k<false>  <<<AGG_BLOCKS, 256, 0, stream>>>(out, nullptr, off, epack,
                                                   weight + (size_t)RR * 256, norm, aggbuf);
    apply_k<false><<<APL_BLOCKS, 256, 0, stream>>>(aggbuf, out, nullptr,
                                                   loop_weight + (size_t)DD * DD, out);
}

// Round 3
// 351.917 us; speedup vs baseline: 3.1703x; 1.3373x over previous
//
#include <hip/hip_runtime.h>
#include <hip/hip_bf16.h>

// Problem constants (match reference)
#define NN 100000      // nodes
#define NE 500000      // edges
#define DD 128         // h_dim
#define RR 230         // relation types
// F.rrelu eval-mode slope = (1/8 + 1/3)/2
#define SLOPE 0.2291666666666666667f

// ===========================================================================
// CSR-by-dst build: histogram -> 2-level exclusive scan -> scatter
// epack[pos] = (src << 8) | type
// ===========================================================================
__global__ __launch_bounds__(256) void hist_k(const int* __restrict__ dst,
                                              int* __restrict__ cnt) {
    int e = blockIdx.x * 256 + threadIdx.x;
    if (e >= NE) return;
    atomicAdd(&cnt[dst[e]], 1);
}

__global__ __launch_bounds__(256) void scan1_k(const int* __restrict__ cnt,
                                               int* __restrict__ off,
                                               int* __restrict__ bsum) {
    __shared__ int sh[256];
    int i = blockIdx.x * 256 + threadIdx.x;
    int v = (i < NN) ? cnt[i] : 0;
    sh[threadIdx.x] = v;
    __syncthreads();
    for (int d = 1; d < 256; d <<= 1) {
        int t = (threadIdx.x >= d) ? sh[threadIdx.x - d] : 0;
        __syncthreads();
        sh[threadIdx.x] += t;
        __syncthreads();
    }
    if (i < NN) off[i] = sh[threadIdx.x] - v;          // exclusive
    if (threadIdx.x == 255) bsum[blockIdx.x] = sh[255];
}

__global__ __launch_bounds__(512) void scan2_k(int* __restrict__ bsum, int nb) {
    __shared__ int sh[512];
    int v = (threadIdx.x < nb) ? bsum[threadIdx.x] : 0;
    sh[threadIdx.x] = v;
    __syncthreads();
    for (int d = 1; d < 512; d <<= 1) {
        int t = (threadIdx.x >= d) ? sh[threadIdx.x - d] : 0;
        __syncthreads();
        sh[threadIdx.x] += t;
        __syncthreads();
    }
    if (threadIdx.x < nb) bsum[threadIdx.x] = sh[threadIdx.x] - v;  // exclusive
}

__global__ __launch_bounds__(256) void scan3_k(int* __restrict__ off,
                                               const int* __restrict__ bsum,
                                               int* __restrict__ cursor) {
    int i = blockIdx.x * 256 + threadIdx.x;
    if (i < NN) {
        int o = off[i] + bsum[blockIdx.x];
        off[i] = o;
        cursor[i] = o;
    }
    if (i == 0) off[NN] = NE;
}

__global__ __launch_bounds__(256) void scat_k(const int* __restrict__ src,
                                              const int* __restrict__ et,
                                              const int* __restrict__ dst,
                                              int* __restrict__ cursor,
                                              int* __restrict__ epack) {
    int e = blockIdx.x * 256 + threadIdx.x;
    if (e >= NE) return;
    int pos = atomicAdd(&cursor[dst[e]], 1);
    epack[pos] = (src[e] << 8) | et[e];
}

// ===========================================================================
// Aggregate: one wave per dst node, no atomics. Lane b owns basis block b.
// agg[n,:] = norm[n] * sum_{e in CSR[n]} blockdiag_msg(h[src_e], w[type_e])
// ===========================================================================
template<bool IND>
__global__ __launch_bounds__(256) void agg_k(const float* __restrict__ h,
                                             const int* __restrict__ nid,
                                             const int* __restrict__ off,
                                             const int* __restrict__ epack,
                                             const float* __restrict__ wl,   // [R,256] this layer
                                             const float* __restrict__ norm,
                                             float* __restrict__ agg) {
    int w    = (blockIdx.x * 256 + threadIdx.x) >> 6;
    int lane = threadIdx.x & 63;
    if (w >= NN) return;
    int e0 = off[w], e1 = off[w + 1];
    float a0 = 0.f, a1 = 0.f;
    for (int e = e0; e < e1; ++e) {
        int p = epack[e];                 // wave-uniform broadcast load
        int s = p >> 8;
        int t = p & 255;
        int row = IND ? nid[s] : s;
        float2 x = *(const float2*)(h + (size_t)row * DD + lane * 2);
        float4 wv = *(const float4*)(wl + (size_t)t * 256 + lane * 4);
        a0 = fmaf(x.x, wv.x, fmaf(x.y, wv.z, a0));
        a1 = fmaf(x.x, wv.y, fmaf(x.y, wv.w, a1));
    }
    float nv = norm[w];
    *(float2*)(agg + (size_t)w * DD + lane * 2) = make_float2(a0 * nv, a1 * nv);
}

// ===========================================================================
// Apply: out[n,:] = rrelu( agg[n,:] + h[n,:] @ W )
// Tiled f32 GEMM: 64-row x 128-col tile / 256-thread block.
// W (128x128, 64 KB) fully LDS-resident; A (h rows) staged TRANSPOSED in
// LDS, k-tiled BK=32, double-buffered. Thread (tx,ty) owns 4 rows x 8 cols.
// In-place safe (h==out): each block reads only rows it later writes, and
// all its reads precede its writes.
// ===========================================================================
#define BK 32
template<bool IND>
__global__ __launch_bounds__(256) void apply_k(const float* __restrict__ agg,
                                               const float* __restrict__ h,
                                               const int* __restrict__ nid,
                                               const float* __restrict__ W,
                                               float* __restrict__ out) {
    __shared__ float Wl[DD * DD];        // 64 KB
    __shared__ float At[2][BK][64];      // 2 x 8 KB, transposed A tiles

    // stage W (coalesced float4)
    {
        const float4* Ws = (const float4*)W;
        float4*       Wd = (float4*)Wl;
        for (int i = threadIdx.x; i < DD * DD / 4; i += 256) Wd[i] = Ws[i];
    }

    const int tid = threadIdx.x;
    const int tx  = tid & 15;            // col group (8 cols)
    const int ty  = tid >> 4;            // row group (4 rows)
    const long n0 = (long)blockIdx.x * 64;

    // staging role: thread stages row si, float4-chunks sc and sc+4 of each k-tile
    const int si = tid >> 2;             // 0..63
    const int sc = tid & 3;              // 0..3
    long srow = n0 + si;
    if (srow >= NN) srow = NN - 1;       // clamp (dup rows, write-guarded later)
    const float* hrow = h + (size_t)(IND ? nid[srow] : (int)srow) * DD;

    float4 r0, r1;
    // prefetch k-tile 0
    r0 = *(const float4*)(hrow + sc * 4);
    r1 = *(const float4*)(hrow + (sc + 4) * 4);
    __syncthreads();                     // W staged
    {   // write tile 0 into At[0] transposed
        #pragma unroll
        for (int m = 0; m < 4; ++m) At[0][sc * 4 + m][si]     = ((const float*)&r0)[m];
        #pragma unroll
        for (int m = 0; m < 4; ++m) At[0][(sc + 4) * 4 + m][si] = ((const float*)&r1)[m];
    }

    float acc[4][8];
    #pragma unroll
    for (int r = 0; r < 4; ++r)
        #pragma unroll
        for (int c = 0; c < 8; ++c) acc[r][c] = 0.f;

    #pragma unroll
    for (int kt = 0; kt < DD / BK; ++kt) {
        __syncthreads();                 // At[kt&1] ready; safe to overwrite At[(kt+1)&1]
        if (kt < DD / BK - 1) {          // issue next-tile global loads (hide under FMAs)
            int k0n = (kt + 1) * BK;
            r0 = *(const float4*)(hrow + k0n + sc * 4);
            r1 = *(const float4*)(hrow + k0n + (sc + 4) * 4);
        }
        const int buf = kt & 1;
        const int k0  = kt * BK;
        #pragma unroll 8
        for (int k = 0; k < BK; ++k) {
            float4 a  = *(const float4*)&At[buf][k][ty * 4];
            float4 b0 = *(const float4*)&Wl[(k0 + k) * DD + tx * 8];
            float4 b1 = *(const float4*)&Wl[(k0 + k) * DD + tx * 8 + 4];
            const float* af = (const float*)&a;
            const float* bf0 = (const float*)&b0;
            const float* bf1 = (const float*)&b1;
            #pragma unroll
            for (int r = 0; r < 4; ++r) {
                #pragma unroll
                for (int c = 0; c < 4; ++c) {
                    acc[r][c]     = fmaf(af[r], bf0[c], acc[r][c]);
                    acc[r][c + 4] = fmaf(af[r], bf1[c], acc[r][c + 4]);
                }
            }
        }
        if (kt < DD / BK - 1) {
            const int nb = (kt + 1) & 1;
            #pragma unroll
            for (int m = 0; m < 4; ++m) At[nb][sc * 4 + m][si]       = ((const float*)&r0)[m];
            #pragma unroll
            for (int m = 0; m < 4; ++m) At[nb][(sc + 4) * 4 + m][si] = ((const float*)&r1)[m];
        }
    }

    // epilogue: rrelu(agg + acc) -> out
    #pragma unroll
    for (int r = 0; r < 4; ++r) {
        long n = n0 + ty * 4 + r;
        if (n >= NN) break;
        const float* ap = agg + (size_t)n * DD + tx * 8;
        float4 g0 = *(const float4*)ap;
        float4 g1 = *(const float4*)(ap + 4);
        float o[8];
        #pragma unroll
        for (int c = 0; c < 4; ++c) {
            o[c]     = ((const float*)&g0)[c] + acc[r][c];
            o[c + 4] = ((const float*)&g1)[c] + acc[r][c + 4];
        }
        #pragma unroll
        for (int c = 0; c < 8; ++c) o[c] = (o[c] >= 0.f) ? o[c] : o[c] * SLOPE;
        float* op = out + (size_t)n * DD + tx * 8;
        *(float4*)op       = make_float4(o[0], o[1], o[2], o[3]);
        *(float4*)(op + 4) = make_float4(o[4], o[5], o[6], o[7]);
    }
}

extern "C" void kernel_launch(void* const* d_in, const int* in_sizes, int n_in,
                              void* d_out, int out_size, void* d_ws, size_t ws_size,
                              hipStream_t stream) {
    const float* ent_embeds  = (const float*)d_in[0];
    // d_in[1] = rel_embeds (unused by the layer)
    const float* weight      = (const float*)d_in[2];   // [L, R, 256]
    const float* loop_weight = (const float*)d_in[3];   // [L, 128, 128]
    const float* norm        = (const float*)d_in[4];   // [N, 1]
    const int*   node_id     = (const int*)d_in[5];
    const int*   edge_type   = (const int*)d_in[6];
    const int*   src         = (const int*)d_in[7];
    const int*   dst         = (const int*)d_in[8];
    float*       out         = (float*)d_out;

    // Workspace layout (~54.5 MB total)
    float* aggbuf = (float*)d_ws;                               // N*D f32 = 51.2 MB
    int*   cnt    = (int*)(aggbuf + (size_t)NN * DD);           // NN
    int*   off    = cnt + NN;                                   // NN+1
    int*   cursor = off + NN + 1;                               // NN
    int*   bsum   = cursor + NN;                                // 512
    int*   epack  = bsum + 512;                                 // NE

    const int NB_E = (NE + 255) / 256;
    const int NB_N = (NN + 255) / 256;

    // ---- CSR build (once; shared by both layers) ----
    hipMemsetAsync(cnt, 0, (size_t)NN * sizeof(int), stream);
    hist_k <<<NB_E, 256, 0, stream>>>(dst, cnt);
    scan1_k<<<NB_N, 256, 0, stream>>>(cnt, off, bsum);
    scan2_k<<<1,    512, 0, stream>>>(bsum, NB_N);
    scan3_k<<<NB_N, 256, 0, stream>>>(off, bsum, cursor);
    scat_k <<<NB_E, 256, 0, stream>>>(src, edge_type, dst, cursor, epack);

    const int AGG_BLOCKS = (NN * 64) / 256;   // one wave per node
    const int APL_BLOCKS = (NN + 63) / 64;    // 64 rows per block

    // ---- layer 0: h0 = ent_embeds[node_id] via double indirection ----
    agg_k<true>  <<<AGG_BLOCKS, 256, 0, stream>>>(ent_embeds, node_id, off, epack,
                                                  weight, norm, aggbuf);
    apply_k<true><<<APL_BLOCKS, 256, 0, stream>>>(aggbuf, ent_embeds, node_id,
                                                  loop_weight, out);

    // ---- layer 1: h1 lives in d_out; apply runs in-place ----
    agg_k<false>  <<<AGG_BLOCKS, 256, 0, stream>>>(out, nullptr, off, epack,
                                                   weight + (size_t)RR * 256, norm, aggbuf);
    apply_k<false><<<APL_BLOCKS, 256, 0, stream>>>(aggbuf, out, nullptr,
                                                   loop_weight + (size_t)DD * DD, out);
}

// Round 4
// 294.349 us; speedup vs baseline: 3.7903x; 1.1956x over previous
//
#include <hip/hip_runtime.h>
#include <hip/hip_bf16.h>

// Problem constants (match reference)
#define NN 100000      // nodes
#define NE 500000      // edges
#define DD 128         // h_dim
#define RR 230         // relation types
// F.rrelu eval-mode slope = (1/8 + 1/3)/2
#define SLOPE 0.2291666666666666667f

// ===========================================================================
// CSR-by-dst build: histogram -> 2-level exclusive scan -> scatter
// epack0[pos] = (node_id[src] << 8) | type   (layer-0 row pre-resolved)
// epack1[pos] = (src           << 8) | type
// ===========================================================================
__global__ __launch_bounds__(256) void hist_k(const int* __restrict__ dst,
                                              int* __restrict__ cnt) {
    int e = blockIdx.x * 256 + threadIdx.x;
    if (e >= NE) return;
    atomicAdd(&cnt[dst[e]], 1);
}

__global__ __launch_bounds__(256) void scan1_k(const int* __restrict__ cnt,
                                               int* __restrict__ off,
                                               int* __restrict__ bsum) {
    __shared__ int sh[256];
    int i = blockIdx.x * 256 + threadIdx.x;
    int v = (i < NN) ? cnt[i] : 0;
    sh[threadIdx.x] = v;
    __syncthreads();
    for (int d = 1; d < 256; d <<= 1) {
        int t = (threadIdx.x >= d) ? sh[threadIdx.x - d] : 0;
        __syncthreads();
        sh[threadIdx.x] += t;
        __syncthreads();
    }
    if (i < NN) off[i] = sh[threadIdx.x] - v;          // exclusive
    if (threadIdx.x == 255) bsum[blockIdx.x] = sh[255];
}

__global__ __launch_bounds__(512) void scan2_k(int* __restrict__ bsum, int nb) {
    __shared__ int sh[512];
    int v = (threadIdx.x < nb) ? bsum[threadIdx.x] : 0;
    sh[threadIdx.x] = v;
    __syncthreads();
    for (int d = 1; d < 512; d <<= 1) {
        int t = (threadIdx.x >= d) ? sh[threadIdx.x - d] : 0;
        __syncthreads();
        sh[threadIdx.x] += t;
        __syncthreads();
    }
    if (threadIdx.x < nb) bsum[threadIdx.x] = sh[threadIdx.x] - v;  // exclusive
}

__global__ __launch_bounds__(256) void scan3_k(int* __restrict__ off,
                                               const int* __restrict__ bsum,
                                               int* __restrict__ cursor) {
    int i = blockIdx.x * 256 + threadIdx.x;
    if (i < NN) {
        int o = off[i] + bsum[blockIdx.x];
        off[i] = o;
        cursor[i] = o;
    }
    if (i == 0) off[NN] = NE;
}

__global__ __launch_bounds__(256) void scat_k(const int* __restrict__ src,
                                              const int* __restrict__ et,
                                              const int* __restrict__ dst,
                                              const int* __restrict__ nid,
                                              int* __restrict__ cursor,
                                              int* __restrict__ epack0,
                                              int* __restrict__ epack1) {
    int e = blockIdx.x * 256 + threadIdx.x;
    if (e >= NE) return;
    int pos = atomicAdd(&cursor[dst[e]], 1);
    int s = src[e];
    int t = et[e];
    epack1[pos] = (s << 8) | t;
    epack0[pos] = (nid[s] << 8) | t;
}

// ===========================================================================
// Aggregate: one wave per dst node, no atomics. Lane b owns basis block b.
// agg[n,:] = norm[n] * sum_{e in CSR[n]} blockdiag_msg(h[row_e], w[type_e])
// Rows pre-resolved in epack. Lane-parallel epack prefetch + 4-wide unroll
// for memory-level parallelism (8 independent gathers in flight).
// ===========================================================================
__global__ __launch_bounds__(256) void agg_k(const float* __restrict__ h,
                                             const int* __restrict__ off,
                                             const int* __restrict__ epack,
                                             const float* __restrict__ wl,   // [R,256] this layer
                                             const float* __restrict__ norm,
                                             float* __restrict__ agg) {
    int w    = (blockIdx.x * 256 + threadIdx.x) >> 6;
    int lane = threadIdx.x & 63;
    if (w >= NN) return;
    int e0 = off[w], e1 = off[w + 1];
    float nv = norm[w];
    float a0 = 0.f, a1 = 0.f;

    for (int base = e0; base < e1; base += 64) {
        int m = e1 - base;
        if (m > 64) m = 64;
        // lane-parallel prefetch of this chunk's packed edges (clamped in-range)
        int pv = epack[base + ((lane < m) ? lane : m - 1)];

        int i = 0;
        for (; i + 4 <= m; i += 4) {
            int p0 = __shfl(pv, i);
            int p1 = __shfl(pv, i + 1);
            int p2 = __shfl(pv, i + 2);
            int p3 = __shfl(pv, i + 3);
            float2 x0 = *(const float2*)(h + (size_t)(p0 >> 8) * DD + lane * 2);
            float2 x1 = *(const float2*)(h + (size_t)(p1 >> 8) * DD + lane * 2);
            float2 x2 = *(const float2*)(h + (size_t)(p2 >> 8) * DD + lane * 2);
            float2 x3 = *(const float2*)(h + (size_t)(p3 >> 8) * DD + lane * 2);
            float4 w0 = *(const float4*)(wl + (size_t)(p0 & 255) * 256 + lane * 4);
            float4 w1 = *(const float4*)(wl + (size_t)(p1 & 255) * 256 + lane * 4);
            float4 w2 = *(const float4*)(wl + (size_t)(p2 & 255) * 256 + lane * 4);
            float4 w3 = *(const float4*)(wl + (size_t)(p3 & 255) * 256 + lane * 4);
            a0 = fmaf(x0.x, w0.x, fmaf(x0.y, w0.z, a0));
            a1 = fmaf(x0.x, w0.y, fmaf(x0.y, w0.w, a1));
            a0 = fmaf(x1.x, w1.x, fmaf(x1.y, w1.z, a0));
            a1 = fmaf(x1.x, w1.y, fmaf(x1.y, w1.w, a1));
            a0 = fmaf(x2.x, w2.x, fmaf(x2.y, w2.z, a0));
            a1 = fmaf(x2.x, w2.y, fmaf(x2.y, w2.w, a1));
            a0 = fmaf(x3.x, w3.x, fmaf(x3.y, w3.z, a0));
            a1 = fmaf(x3.x, w3.y, fmaf(x3.y, w3.w, a1));
        }
        for (; i < m; ++i) {
            int p = __shfl(pv, i);
            float2 x = *(const float2*)(h + (size_t)(p >> 8) * DD + lane * 2);
            float4 wv = *(const float4*)(wl + (size_t)(p & 255) * 256 + lane * 4);
            a0 = fmaf(x.x, wv.x, fmaf(x.y, wv.z, a0));
            a1 = fmaf(x.x, wv.y, fmaf(x.y, wv.w, a1));
        }
    }
    *(float2*)(agg + (size_t)w * DD + lane * 2) = make_float2(a0 * nv, a1 * nv);
}

// ===========================================================================
// Apply: out[n,:] = rrelu( agg[n,:] + h[n,:] @ W )
// Tiled f32 GEMM: 64-row x 128-col tile / 256-thread block. W LDS-resident,
// A staged transposed in LDS, BK=32 double-buffered. In-place safe.
// ===========================================================================
#define BK 32
template<bool IND>
__global__ __launch_bounds__(256) void apply_k(const float* __restrict__ agg,
                                               const float* __restrict__ h,
                                               const int* __restrict__ nid,
                                               const float* __restrict__ W,
                                               float* __restrict__ out) {
    __shared__ float Wl[DD * DD];        // 64 KB
    __shared__ float At[2][BK][64];      // 2 x 8 KB, transposed A tiles

    {
        const float4* Ws = (const float4*)W;
        float4*       Wd = (float4*)Wl;
        for (int i = threadIdx.x; i < DD * DD / 4; i += 256) Wd[i] = Ws[i];
    }

    const int tid = threadIdx.x;
    const int tx  = tid & 15;            // col group (8 cols)
    const int ty  = tid >> 4;            // row group (4 rows)
    const long n0 = (long)blockIdx.x * 64;

    const int si = tid >> 2;             // staging row 0..63
    const int sc = tid & 3;              // staging chunk 0..3
    long srow = n0 + si;
    if (srow >= NN) srow = NN - 1;
    const float* hrow = h + (size_t)(IND ? nid[srow] : (int)srow) * DD;

    float4 r0, r1;
    r0 = *(const float4*)(hrow + sc * 4);
    r1 = *(const float4*)(hrow + (sc + 4) * 4);
    __syncthreads();
    {
        #pragma unroll
        for (int m = 0; m < 4; ++m) At[0][sc * 4 + m][si]       = ((const float*)&r0)[m];
        #pragma unroll
        for (int m = 0; m < 4; ++m) At[0][(sc + 4) * 4 + m][si] = ((const float*)&r1)[m];
    }

    float acc[4][8];
    #pragma unroll
    for (int r = 0; r < 4; ++r)
        #pragma unroll
        for (int c = 0; c < 8; ++c) acc[r][c] = 0.f;

    #pragma unroll
    for (int kt = 0; kt < DD / BK; ++kt) {
        __syncthreads();
        if (kt < DD / BK - 1) {
            int k0n = (kt + 1) * BK;
            r0 = *(const float4*)(hrow + k0n + sc * 4);
            r1 = *(const float4*)(hrow + k0n + (sc + 4) * 4);
        }
        const int buf = kt & 1;
        const int k0  = kt * BK;
        #pragma unroll 8
        for (int k = 0; k < BK; ++k) {
            float4 a  = *(const float4*)&At[buf][k][ty * 4];
            float4 b0 = *(const float4*)&Wl[(k0 + k) * DD + tx * 8];
            float4 b1 = *(const float4*)&Wl[(k0 + k) * DD + tx * 8 + 4];
            const float* af  = (const float*)&a;
            const float* bf0 = (const float*)&b0;
            const float* bf1 = (const float*)&b1;
            #pragma unroll
            for (int r = 0; r < 4; ++r) {
                #pragma unroll
                for (int c = 0; c < 4; ++c) {
                    acc[r][c]     = fmaf(af[r], bf0[c], acc[r][c]);
                    acc[r][c + 4] = fmaf(af[r], bf1[c], acc[r][c + 4]);
                }
            }
        }
        if (kt < DD / BK - 1) {
            const int nb = (kt + 1) & 1;
            #pragma unroll
            for (int m = 0; m < 4; ++m) At[nb][sc * 4 + m][si]       = ((const float*)&r0)[m];
            #pragma unroll
            for (int m = 0; m < 4; ++m) At[nb][(sc + 4) * 4 + m][si] = ((const float*)&r1)[m];
        }
    }

    #pragma unroll
    for (int r = 0; r < 4; ++r) {
        long n = n0 + ty * 4 + r;
        if (n >= NN) break;
        const float* ap = agg + (size_t)n * DD + tx * 8;
        float4 g0 = *(const float4*)ap;
        float4 g1 = *(const float4*)(ap + 4);
        float o[8];
        #pragma unroll
        for (int c = 0; c < 4; ++c) {
            o[c]     = ((const float*)&g0)[c] + acc[r][c];
            o[c + 4] = ((const float*)&g1)[c] + acc[r][c + 4];
        }
        #pragma unroll
        for (int c = 0; c < 8; ++c) o[c] = (o[c] >= 0.f) ? o[c] : o[c] * SLOPE;
        float* op = out + (size_t)n * DD + tx * 8;
        *(float4*)op       = make_float4(o[0], o[1], o[2], o[3]);
        *(float4*)(op + 4) = make_float4(o[4], o[5], o[6], o[7]);
    }
}

extern "C" void kernel_launch(void* const* d_in, const int* in_sizes, int n_in,
                              void* d_out, int out_size, void* d_ws, size_t ws_size,
                              hipStream_t stream) {
    const float* ent_embeds  = (const float*)d_in[0];
    // d_in[1] = rel_embeds (unused by the layer)
    const float* weight      = (const float*)d_in[2];   // [L, R, 256]
    const float* loop_weight = (const float*)d_in[3];   // [L, 128, 128]
    const float* norm        = (const float*)d_in[4];   // [N, 1]
    const int*   node_id     = (const int*)d_in[5];
    const int*   edge_type   = (const int*)d_in[6];
    const int*   src         = (const int*)d_in[7];
    const int*   dst         = (const int*)d_in[8];
    float*       out         = (float*)d_out;

    // Workspace layout (~59 MB total; >=102 MB proven available)
    float* aggbuf = (float*)d_ws;                               // N*D f32 = 51.2 MB
    int*   cnt    = (int*)(aggbuf + (size_t)NN * DD);           // NN
    int*   off    = cnt + NN;                                   // NN+1
    int*   cursor = off + NN + 1;                               // NN
    int*   bsum   = cursor + NN;                                // 512
    int*   epack0 = bsum + 512;                                 // NE (layer-0 rows)
    int*   epack1 = epack0 + NE;                                // NE (layer-1 rows)

    const int NB_E = (NE + 255) / 256;
    const int NB_N = (NN + 255) / 256;

    // ---- CSR build (once; shared by both layers) ----
    hipMemsetAsync(cnt, 0, (size_t)NN * sizeof(int), stream);
    hist_k <<<NB_E, 256, 0, stream>>>(dst, cnt);
    scan1_k<<<NB_N, 256, 0, stream>>>(cnt, off, bsum);
    scan2_k<<<1,    512, 0, stream>>>(bsum, NB_N);
    scan3_k<<<NB_N, 256, 0, stream>>>(off, bsum, cursor);
    scat_k <<<NB_E, 256, 0, stream>>>(src, edge_type, dst, node_id, cursor, epack0, epack1);

    const int AGG_BLOCKS = (NN * 64) / 256;   // one wave per node
    const int APL_BLOCKS = (NN + 63) / 64;    // 64 rows per block

    // ---- layer 0: h0 rows pre-resolved into epack0 ----
    agg_k        <<<AGG_BLOCKS, 256, 0, stream>>>(ent_embeds, off, epack0,
                                                  weight, norm, aggbuf);
    apply_k<true><<<APL_BLOCKS, 256, 0, stream>>>(aggbuf, ent_embeds, node_id,
                                                  loop_weight, out);

    // ---- layer 1: h1 lives in d_out; apply runs in-place ----
    agg_k         <<<AGG_BLOCKS, 256, 0, stream>>>(out, off, epack1,
                                                   weight + (size_t)RR * 256, norm, aggbuf);
    apply_k<false><<<APL_BLOCKS, 256, 0, stream>>>(aggbuf, out, nullptr,
                                                   loop_weight + (size_t)DD * DD, out);
}

// Round 5
// 278.103 us; speedup vs baseline: 4.0117x; 1.0584x over previous
//
#include <hip/hip_runtime.h>
#include <hip/hip_bf16.h>

// Problem constants (match reference)
#define NN 100000      // nodes
#define NE 500000      // edges
#define DD 128         // h_dim
#define RR 230         // relation types
// F.rrelu eval-mode slope = (1/8 + 1/3)/2
#define SLOPE 0.2291666666666666667f

// ===========================================================================
// CSR-by-dst build: histogram -> 2-level exclusive scan -> scatter
// epack0[pos] = (node_id[src] << 8) | type   (layer-0 row pre-resolved)
// epack1[pos] = (src           << 8) | type
// ===========================================================================
__global__ __launch_bounds__(256) void hist_k(const int* __restrict__ dst,
                                              int* __restrict__ cnt) {
    int e = blockIdx.x * 256 + threadIdx.x;
    if (e >= NE) return;
    atomicAdd(&cnt[dst[e]], 1);
}

__global__ __launch_bounds__(256) void scan1_k(const int* __restrict__ cnt,
                                               int* __restrict__ off,
                                               int* __restrict__ bsum) {
    __shared__ int sh[256];
    int i = blockIdx.x * 256 + threadIdx.x;
    int v = (i < NN) ? cnt[i] : 0;
    sh[threadIdx.x] = v;
    __syncthreads();
    for (int d = 1; d < 256; d <<= 1) {
        int t = (threadIdx.x >= d) ? sh[threadIdx.x - d] : 0;
        __syncthreads();
        sh[threadIdx.x] += t;
        __syncthreads();
    }
    if (i < NN) off[i] = sh[threadIdx.x] - v;          // exclusive
    if (threadIdx.x == 255) bsum[blockIdx.x] = sh[255];
}

__global__ __launch_bounds__(512) void scan2_k(int* __restrict__ bsum, int nb) {
    __shared__ int sh[512];
    int v = (threadIdx.x < nb) ? bsum[threadIdx.x] : 0;
    sh[threadIdx.x] = v;
    __syncthreads();
    for (int d = 1; d < 512; d <<= 1) {
        int t = (threadIdx.x >= d) ? sh[threadIdx.x - d] : 0;
        __syncthreads();
        sh[threadIdx.x] += t;
        __syncthreads();
    }
    if (threadIdx.x < nb) bsum[threadIdx.x] = sh[threadIdx.x] - v;  // exclusive
}

__global__ __launch_bounds__(256) void scan3_k(int* __restrict__ off,
                                               const int* __restrict__ bsum,
                                               int* __restrict__ cursor) {
    int i = blockIdx.x * 256 + threadIdx.x;
    if (i < NN) {
        int o = off[i] + bsum[blockIdx.x];
        off[i] = o;
        cursor[i] = o;
    }
    if (i == 0) off[NN] = NE;
}

__global__ __launch_bounds__(256) void scat_k(const int* __restrict__ src,
                                              const int* __restrict__ et,
                                              const int* __restrict__ dst,
                                              const int* __restrict__ nid,
                                              int* __restrict__ cursor,
                                              int* __restrict__ epack0,
                                              int* __restrict__ epack1) {
    int e = blockIdx.x * 256 + threadIdx.x;
    if (e >= NE) return;
    int pos = atomicAdd(&cursor[dst[e]], 1);
    int s = src[e];
    int t = et[e];
    epack1[pos] = (s << 8) | t;
    epack0[pos] = (nid[s] << 8) | t;
}

// ===========================================================================
// Aggregate: one wave per dst node, no atomics. Lane b owns basis block b.
// Rows pre-resolved in epack; lane-parallel prefetch + 4-wide unroll for MLP.
// ===========================================================================
__global__ __launch_bounds__(256) void agg_k(const float* __restrict__ h,
                                             const int* __restrict__ off,
                                             const int* __restrict__ epack,
                                             const float* __restrict__ wl,   // [R,256] this layer
                                             const float* __restrict__ norm,
                                             float* __restrict__ agg) {
    int w    = (blockIdx.x * 256 + threadIdx.x) >> 6;
    int lane = threadIdx.x & 63;
    if (w >= NN) return;
    int e0 = off[w], e1 = off[w + 1];
    float nv = norm[w];
    float a0 = 0.f, a1 = 0.f;

    for (int base = e0; base < e1; base += 64) {
        int m = e1 - base;
        if (m > 64) m = 64;
        int pv = epack[base + ((lane < m) ? lane : m - 1)];

        int i = 0;
        for (; i + 4 <= m; i += 4) {
            int p0 = __shfl(pv, i);
            int p1 = __shfl(pv, i + 1);
            int p2 = __shfl(pv, i + 2);
            int p3 = __shfl(pv, i + 3);
            float2 x0 = *(const float2*)(h + (size_t)(p0 >> 8) * DD + lane * 2);
            float2 x1 = *(const float2*)(h + (size_t)(p1 >> 8) * DD + lane * 2);
            float2 x2 = *(const float2*)(h + (size_t)(p2 >> 8) * DD + lane * 2);
            float2 x3 = *(const float2*)(h + (size_t)(p3 >> 8) * DD + lane * 2);
            float4 w0 = *(const float4*)(wl + (size_t)(p0 & 255) * 256 + lane * 4);
            float4 w1 = *(const float4*)(wl + (size_t)(p1 & 255) * 256 + lane * 4);
            float4 w2 = *(const float4*)(wl + (size_t)(p2 & 255) * 256 + lane * 4);
            float4 w3 = *(const float4*)(wl + (size_t)(p3 & 255) * 256 + lane * 4);
            a0 = fmaf(x0.x, w0.x, fmaf(x0.y, w0.z, a0));
            a1 = fmaf(x0.x, w0.y, fmaf(x0.y, w0.w, a1));
            a0 = fmaf(x1.x, w1.x, fmaf(x1.y, w1.z, a0));
            a1 = fmaf(x1.x, w1.y, fmaf(x1.y, w1.w, a1));
            a0 = fmaf(x2.x, w2.x, fmaf(x2.y, w2.z, a0));
            a1 = fmaf(x2.x, w2.y, fmaf(x2.y, w2.w, a1));
            a0 = fmaf(x3.x, w3.x, fmaf(x3.y, w3.z, a0));
            a1 = fmaf(x3.x, w3.y, fmaf(x3.y, w3.w, a1));
        }
        for (; i < m; ++i) {
            int p = __shfl(pv, i);
            float2 x = *(const float2*)(h + (size_t)(p >> 8) * DD + lane * 2);
            float4 wv = *(const float4*)(wl + (size_t)(p & 255) * 256 + lane * 4);
            a0 = fmaf(x.x, wv.x, fmaf(x.y, wv.z, a0));
            a1 = fmaf(x.x, wv.y, fmaf(x.y, wv.w, a1));
        }
    }
    *(float2*)(agg + (size_t)w * DD + lane * 2) = make_float2(a0 * nv, a1 * nv);
}

// ===========================================================================
// Apply: out[n,:] = rrelu( agg[n,:] + h[n,:] @ W )
// 128x128 tile / 256 threads, 8x8 micro-tile. Both A and W k-tiled (BK=16)
// and double-buffered in LDS (32 KB total -> 4 blocks/CU). LDS layout is
// XOR-swizzled on 16-B units (j -> j ^ (j>>3)) so the 16-lane float4 read
// fans cover each bank-quad exactly 2x (2-way = free).
// In-place safe (h==out): block reads only rows it later writes; all reads
// precede its writes.
// ===========================================================================
#define BK 16
__device__ __forceinline__ int swzu(int j) { return j ^ (j >> 3); }   // 16B-unit swizzle

template<bool IND>
__global__ __launch_bounds__(256, 4) void apply_k(const float* __restrict__ agg,
                                                  const float* __restrict__ h,
                                                  const int* __restrict__ nid,
                                                  const float* __restrict__ W,
                                                  float* __restrict__ out) {
    __shared__ float Ash[2][BK * DD];    // 2 x 8 KB, transposed: (k, row), swizzled
    __shared__ float Wsh[2][BK * DD];    // 2 x 8 KB, natural:    (k, col), swizzled

    const int tid = threadIdx.x;
    const int tx  = tid & 15;            // col group: cols tx*8 .. tx*8+7
    const int ty  = tid >> 4;            // row group: rows ty*8 .. ty*8+7
    const long n0 = (long)blockIdx.x * 128;

    // ---- staging roles ----
    // A: thread covers row srow_l (0..127), half sc (k-offsets sc*8 .. sc*8+7)
    const int srow_l = tid >> 1;
    const int sc     = tid & 1;
    long srow = n0 + srow_l;
    if (srow >= NN) srow = NN - 1;       // clamp (dup rows; writes guarded)
    const float* hrow = h + (size_t)(IND ? nid[srow] : (int)srow) * DD;
    const int a_rs = (swzu(srow_l >> 2) << 2) + (srow_l & 3);  // swizzled row slot

    // W: thread copies float4 linear indices tid and tid+256 of each 512-f4 tile
    const float4* Wv = (const float4*)W;

    float4 ar0, ar1, wr0, wr1;
    // prefetch k-tile 0
    ar0 = *(const float4*)(hrow + sc * 8);
    ar1 = *(const float4*)(hrow + sc * 8 + 4);
    {
        int i0 = tid, i1 = tid + 256;
        wr0 = Wv[(i0 >> 5) * 32 + (i0 & 31)];
        wr1 = Wv[(i1 >> 5) * 32 + (i1 & 31)];
    }
    // store tile 0
    {
        #pragma unroll
        for (int m = 0; m < 4; ++m) Ash[0][(sc * 8 + m) * DD + a_rs]     = ((const float*)&ar0)[m];
        #pragma unroll
        for (int m = 0; m < 4; ++m) Ash[0][(sc * 8 + 4 + m) * DD + a_rs] = ((const float*)&ar1)[m];
        int i0 = tid, i1 = tid + 256;
        *(float4*)&Wsh[0][(i0 >> 5) * DD + swzu(i0 & 31) * 4] = wr0;
        *(float4*)&Wsh[0][(i1 >> 5) * DD + swzu(i1 & 31) * 4] = wr1;
    }

    // swizzled read bases (16B units): A rows ty*8 -> units 2ty,2ty+1; W cols tx*8
    const int aB0 = swzu(2 * ty) * 4;
    const int aB1 = swzu(2 * ty + 1) * 4;
    const int wB0 = swzu(2 * tx) * 4;
    const int wB1 = swzu(2 * tx + 1) * 4;

    float acc[8][8];
    #pragma unroll
    for (int r = 0; r < 8; ++r)
        #pragma unroll
        for (int c = 0; c < 8; ++c) acc[r][c] = 0.f;

    for (int kt = 0; kt < DD / BK; ++kt) {
        __syncthreads();
        if (kt < DD / BK - 1) {          // prefetch next tile (global -> regs)
            int k0n = (kt + 1) * BK;
            ar0 = *(const float4*)(hrow + k0n + sc * 8);
            ar1 = *(const float4*)(hrow + k0n + sc * 8 + 4);
            int i0 = tid, i1 = tid + 256;
            wr0 = Wv[(k0n >> 4) * 512 + (i0 >> 5) * 32 + (i0 & 31)];
            wr1 = Wv[(k0n >> 4) * 512 + (i1 >> 5) * 32 + (i1 & 31)];
        }
        const float* Ab = Ash[kt & 1];
        const float* Wb = Wsh[kt & 1];
        #pragma unroll 4
        for (int k = 0; k < BK; ++k) {
            float4 a0 = *(const float4*)&Ab[k * DD + aB0];   // rows ty*8..+3
            float4 a1 = *(const float4*)&Ab[k * DD + aB1];   // rows ty*8+4..+7
            float4 w0 = *(const float4*)&Wb[k * DD + wB0];   // cols tx*8..+3
            float4 w1 = *(const float4*)&Wb[k * DD + wB1];   // cols tx*8+4..+7
            const float* af = (const float*)&a0;
            const float* ag = (const float*)&a1;
            const float* wf = (const float*)&w0;
            const float* wg = (const float*)&w1;
            #pragma unroll
            for (int r = 0; r < 4; ++r) {
                #pragma unroll
                for (int c = 0; c < 4; ++c) {
                    acc[r][c]         = fmaf(af[r], wf[c], acc[r][c]);
                    acc[r][c + 4]     = fmaf(af[r], wg[c], acc[r][c + 4]);
                    acc[r + 4][c]     = fmaf(ag[r], wf[c], acc[r + 4][c]);
                    acc[r + 4][c + 4] = fmaf(ag[r], wg[c], acc[r + 4][c + 4]);
                }
            }
        }
        if (kt < DD / BK - 1) {          // store prefetched tile into other buffer
            const int nb = (kt + 1) & 1;
            #pragma unroll
            for (int m = 0; m < 4; ++m) Ash[nb][(sc * 8 + m) * DD + a_rs]     = ((const float*)&ar0)[m];
            #pragma unroll
            for (int m = 0; m < 4; ++m) Ash[nb][(sc * 8 + 4 + m) * DD + a_rs] = ((const float*)&ar1)[m];
            int i0 = tid, i1 = tid + 256;
            *(float4*)&Wsh[nb][(i0 >> 5) * DD + swzu(i0 & 31) * 4] = wr0;
            *(float4*)&Wsh[nb][(i1 >> 5) * DD + swzu(i1 & 31) * 4] = wr1;
        }
    }

    // epilogue: rrelu(agg + acc) -> out (8 rows x 8 cols per thread)
    #pragma unroll
    for (int r = 0; r < 8; ++r) {
        long n = n0 + ty * 8 + r;
        if (n >= NN) break;
        const float* ap = agg + (size_t)n * DD + tx * 8;
        float4 g0 = *(const float4*)ap;
        float4 g1 = *(const float4*)(ap + 4);
        float o[8];
        #pragma unroll
        for (int c = 0; c < 4; ++c) {
            o[c]     = ((const float*)&g0)[c] + acc[r][c];
            o[c + 4] = ((const float*)&g1)[c] + acc[r][c + 4];
        }
        #pragma unroll
        for (int c = 0; c < 8; ++c) o[c] = (o[c] >= 0.f) ? o[c] : o[c] * SLOPE;
        float* op = out + (size_t)n * DD + tx * 8;
        *(float4*)op       = make_float4(o[0], o[1], o[2], o[3]);
        *(float4*)(op + 4) = make_float4(o[4], o[5], o[6], o[7]);
    }
}

extern "C" void kernel_launch(void* const* d_in, const int* in_sizes, int n_in,
                              void* d_out, int out_size, void* d_ws, size_t ws_size,
                              hipStream_t stream) {
    const float* ent_embeds  = (const float*)d_in[0];
    // d_in[1] = rel_embeds (unused by the layer)
    const float* weight      = (const float*)d_in[2];   // [L, R, 256]
    const float* loop_weight = (const float*)d_in[3];   // [L, 128, 128]
    const float* norm        = (const float*)d_in[4];   // [N, 1]
    const int*   node_id     = (const int*)d_in[5];
    const int*   edge_type   = (const int*)d_in[6];
    const int*   src         = (const int*)d_in[7];
    const int*   dst         = (const int*)d_in[8];
    float*       out         = (float*)d_out;

    // Workspace layout (~59 MB total)
    float* aggbuf = (float*)d_ws;                               // N*D f32 = 51.2 MB
    int*   cnt    = (int*)(aggbuf + (size_t)NN * DD);           // NN
    int*   off    = cnt + NN;                                   // NN+1
    int*   cursor = off + NN + 1;                               // NN
    int*   bsum   = cursor + NN;                                // 512
    int*   epack0 = bsum + 512;                                 // NE (layer-0 rows)
    int*   epack1 = epack0 + NE;                                // NE (layer-1 rows)

    const int NB_E = (NE + 255) / 256;
    const int NB_N = (NN + 255) / 256;

    // ---- CSR build (once; shared by both layers) ----
    hipMemsetAsync(cnt, 0, (size_t)NN * sizeof(int), stream);
    hist_k <<<NB_E, 256, 0, stream>>>(dst, cnt);
    scan1_k<<<NB_N, 256, 0, stream>>>(cnt, off, bsum);
    scan2_k<<<1,    512, 0, stream>>>(bsum, NB_N);
    scan3_k<<<NB_N, 256, 0, stream>>>(off, bsum, cursor);
    scat_k <<<NB_E, 256, 0, stream>>>(src, edge_type, dst, node_id, cursor, epack0, epack1);

    const int AGG_BLOCKS = (NN * 64) / 256;    // one wave per node
    const int APL_BLOCKS = (NN + 127) / 128;   // 128 rows per block

    // ---- layer 0: h0 rows pre-resolved into epack0 ----
    agg_k        <<<AGG_BLOCKS, 256, 0, stream>>>(ent_embeds, off, epack0,
                                                  weight, norm, aggbuf);
    apply_k<true><<<APL_BLOCKS, 256, 0, stream>>>(aggbuf, ent_embeds, node_id,
                                                  loop_weight, out);

    // ---- layer 1: h1 lives in d_out; apply runs in-place ----
    agg_k         <<<AGG_BLOCKS, 256, 0, stream>>>(out, off, epack1,
                                                   weight + (size_t)RR * 256, norm, aggbuf);
    apply_k<false><<<APL_BLOCKS, 256, 0, stream>>>(aggbuf, out, nullptr,
                                                   loop_weight + (size_t)DD * DD, out);
}

// Round 6
// 250.480 us; speedup vs baseline: 4.4541x; 1.1103x over previous
//
#include <hip/hip_runtime.h>
#include <hip/hip_bf16.h>

// Problem constants (match reference)
#define NN 100000      // nodes
#define NE 500000      // edges
#define DD 128         // h_dim
#define RR 230         // relation types
// F.rrelu eval-mode slope = (1/8 + 1/3)/2
#define SLOPE 0.2291666666666666667f

typedef __attribute__((ext_vector_type(8))) short short8;
typedef __attribute__((ext_vector_type(4))) float f32x4;

__device__ __forceinline__ short f2bf(float f) {   // RNE f32 -> bf16 bits
    unsigned u = __float_as_uint(f);
    u += 0x7fffu + ((u >> 16) & 1u);
    return (short)(u >> 16);
}

// ===========================================================================
// CSR-by-dst build: histogram -> 2-level exclusive scan -> scatter
// epack0[pos] = (node_id[src] << 8) | type ; epack1[pos] = (src << 8) | type
// ===========================================================================
__global__ __launch_bounds__(256) void hist_k(const int* __restrict__ dst,
                                              int* __restrict__ cnt) {
    int e = blockIdx.x * 256 + threadIdx.x;
    if (e >= NE) return;
    atomicAdd(&cnt[dst[e]], 1);
}

__global__ __launch_bounds__(256) void scan1_k(const int* __restrict__ cnt,
                                               int* __restrict__ off,
                                               int* __restrict__ bsum) {
    __shared__ int sh[256];
    int i = blockIdx.x * 256 + threadIdx.x;
    int v = (i < NN) ? cnt[i] : 0;
    sh[threadIdx.x] = v;
    __syncthreads();
    for (int d = 1; d < 256; d <<= 1) {
        int t = (threadIdx.x >= d) ? sh[threadIdx.x - d] : 0;
        __syncthreads();
        sh[threadIdx.x] += t;
        __syncthreads();
    }
    if (i < NN) off[i] = sh[threadIdx.x] - v;          // exclusive
    if (threadIdx.x == 255) bsum[blockIdx.x] = sh[255];
}

__global__ __launch_bounds__(512) void scan2_k(int* __restrict__ bsum, int nb) {
    __shared__ int sh[512];
    int v = (threadIdx.x < nb) ? bsum[threadIdx.x] : 0;
    sh[threadIdx.x] = v;
    __syncthreads();
    for (int d = 1; d < 512; d <<= 1) {
        int t = (threadIdx.x >= d) ? sh[threadIdx.x - d] : 0;
        __syncthreads();
        sh[threadIdx.x] += t;
        __syncthreads();
    }
    if (threadIdx.x < nb) bsum[threadIdx.x] = sh[threadIdx.x] - v;  // exclusive
}

__global__ __launch_bounds__(256) void scan3_k(int* __restrict__ off,
                                               const int* __restrict__ bsum,
                                               int* __restrict__ cursor) {
    int i = blockIdx.x * 256 + threadIdx.x;
    if (i < NN) {
        int o = off[i] + bsum[blockIdx.x];
        off[i] = o;
        cursor[i] = o;
    }
    if (i == 0) off[NN] = NE;
}

__global__ __launch_bounds__(256) void scat_k(const int* __restrict__ src,
                                              const int* __restrict__ et,
                                              const int* __restrict__ dst,
                                              const int* __restrict__ nid,
                                              int* __restrict__ cursor,
                                              int* __restrict__ epack0,
                                              int* __restrict__ epack1) {
    int e = blockIdx.x * 256 + threadIdx.x;
    if (e >= NE) return;
    int pos = atomicAdd(&cursor[dst[e]], 1);
    int s = src[e];
    int t = et[e];
    epack1[pos] = (s << 8) | t;
    epack0[pos] = (nid[s] << 8) | t;
}

// ===========================================================================
// wprep: loop_weight[l][k][c] f32 -> Wt[l][c][k] bf16, XOR-swizzled on
// 8-elem (16B) units: phys unit = u ^ (c&7). One thread per (l,c,u).
// ===========================================================================
__global__ __launch_bounds__(256) void wprep_k(const float* __restrict__ lw,
                                               short* __restrict__ wt) {
    int gid = blockIdx.x * 256 + threadIdx.x;
    if (gid >= 2 * DD * 16) return;
    int l   = gid >> 11;
    int rem = gid & 2047;
    int c   = rem >> 4;
    int u   = rem & 15;
    const float* wsrc = lw + l * DD * DD + c;   // stride DD over k
    short8 v;
    #pragma unroll
    for (int j = 0; j < 8; ++j) v[j] = f2bf(wsrc[(u * 8 + j) * DD]);
    *(short8*)(wt + (size_t)l * DD * DD + c * DD + ((u ^ (c & 7)) << 3)) = v;
}

// ===========================================================================
// Aggregate: one wave per dst node. 32 lanes per edge (lane covers 4 dims =
// 2 basis blocks), half-waves process interleaved edges -> 8 edges per
// iteration, 12 gathers in flight. Final cross-half combine via shfl_xor.
// ===========================================================================
__global__ __launch_bounds__(256) void agg_k(const float* __restrict__ h,
                                             const int* __restrict__ off,
                                             const int* __restrict__ epack,
                                             const float* __restrict__ wl,   // [R,256] this layer
                                             const float* __restrict__ norm,
                                             float* __restrict__ agg) {
    int n    = (blockIdx.x * 256 + threadIdx.x) >> 6;
    int lane = threadIdx.x & 63;
    int hl   = lane & 31;        // dim group: dims 4hl..4hl+3 (blocks 2hl, 2hl+1)
    int h2   = lane >> 5;        // half: handles edges base+2j+h2
    if (n >= NN) return;
    int e0 = off[n];
    int m  = off[n + 1] - e0;
    float a0 = 0.f, a1 = 0.f, a2 = 0.f, a3 = 0.f;

    for (int base = 0; base < m; base += 64) {
        int cnt = m - base;
        if (cnt > 64) cnt = 64;
        int pv = epack[e0 + base + ((lane < cnt) ? lane : cnt - 1)];

        for (int j = 0; j < cnt; j += 8) {
            int i0 = j + 0 + h2, i1 = j + 2 + h2, i2 = j + 4 + h2, i3 = j + 6 + h2;
            int p0 = __shfl(pv, (i0 < cnt) ? i0 : cnt - 1);
            int p1 = __shfl(pv, (i1 < cnt) ? i1 : cnt - 1);
            int p2 = __shfl(pv, (i2 < cnt) ? i2 : cnt - 1);
            int p3 = __shfl(pv, (i3 < cnt) ? i3 : cnt - 1);
            float s0 = (i0 < cnt) ? 1.f : 0.f;
            float s1 = (i1 < cnt) ? 1.f : 0.f;
            float s2 = (i2 < cnt) ? 1.f : 0.f;
            float s3 = (i3 < cnt) ? 1.f : 0.f;
            float4 x0 = *(const float4*)(h + (size_t)(p0 >> 8) * DD + hl * 4);
            float4 x1 = *(const float4*)(h + (size_t)(p1 >> 8) * DD + hl * 4);
            float4 x2 = *(const float4*)(h + (size_t)(p2 >> 8) * DD + hl * 4);
            float4 x3 = *(const float4*)(h + (size_t)(p3 >> 8) * DD + hl * 4);
            const float* q0 = wl + (size_t)(p0 & 255) * 256 + hl * 8;
            const float* q1 = wl + (size_t)(p1 & 255) * 256 + hl * 8;
            const float* q2 = wl + (size_t)(p2 & 255) * 256 + hl * 8;
            const float* q3 = wl + (size_t)(p3 & 255) * 256 + hl * 8;
            float4 wa0 = *(const float4*)q0, wb0 = *(const float4*)(q0 + 4);
            float4 wa1 = *(const float4*)q1, wb1 = *(const float4*)(q1 + 4);
            float4 wa2 = *(const float4*)q2, wb2 = *(const float4*)(q2 + 4);
            float4 wa3 = *(const float4*)q3, wb3 = *(const float4*)(q3 + 4);
            // block 2hl: out(4hl,4hl+1) from in(x.x,x.y); block 2hl+1: out(4hl+2,4hl+3) from (x.z,x.w)
            // w layout per block: (i0o0, i0o1, i1o0, i1o1)
            x0.x *= s0; x0.y *= s0; x0.z *= s0; x0.w *= s0;
            x1.x *= s1; x1.y *= s1; x1.z *= s1; x1.w *= s1;
            x2.x *= s2; x2.y *= s2; x2.z *= s2; x2.w *= s2;
            x3.x *= s3; x3.y *= s3; x3.z *= s3; x3.w *= s3;
            a0 = fmaf(x0.x, wa0.x, fmaf(x0.y, wa0.z, a0));
            a1 = fmaf(x0.x, wa0.y, fmaf(x0.y, wa0.w, a1));
            a2 = fmaf(x0.z, wb0.x, fmaf(x0.w, wb0.z, a2));
            a3 = fmaf(x0.z, wb0.y, fmaf(x0.w, wb0.w, a3));
            a0 = fmaf(x1.x, wa1.x, fmaf(x1.y, wa1.z, a0));
            a1 = fmaf(x1.x, wa1.y, fmaf(x1.y, wa1.w, a1));
            a2 = fmaf(x1.z, wb1.x, fmaf(x1.w, wb1.z, a2));
            a3 = fmaf(x1.z, wb1.y, fmaf(x1.w, wb1.w, a3));
            a0 = fmaf(x2.x, wa2.x, fmaf(x2.y, wa2.z, a0));
            a1 = fmaf(x2.x, wa2.y, fmaf(x2.y, wa2.w, a1));
            a2 = fmaf(x2.z, wb2.x, fmaf(x2.w, wb2.z, a2));
            a3 = fmaf(x2.z, wb2.y, fmaf(x2.w, wb2.w, a3));
            a0 = fmaf(x3.x, wa3.x, fmaf(x3.y, wa3.z, a0));
            a1 = fmaf(x3.x, wa3.y, fmaf(x3.y, wa3.w, a1));
            a2 = fmaf(x3.z, wb3.x, fmaf(x3.w, wb3.z, a2));
            a3 = fmaf(x3.z, wb3.y, fmaf(x3.w, wb3.w, a3));
        }
    }
    // combine halves (even/odd edges) for the same dims
    a0 += __shfl_xor(a0, 32);
    a1 += __shfl_xor(a1, 32);
    a2 += __shfl_xor(a2, 32);
    a3 += __shfl_xor(a3, 32);
    if (h2 == 0) {
        float nv = norm[n];
        *(float4*)(agg + (size_t)n * DD + hl * 4) =
            make_float4(a0 * nv, a1 * nv, a2 * nv, a3 * nv);
    }
}

// ===========================================================================
// Apply: out[n,:] = rrelu( agg[n,:] + h[n,:] @ W )  via bf16 MFMA 16x16x32.
// Block = 256 thr (4 waves), tile 128 rows x 128 cols, K=128 in one shot.
// A: f32 h rows converted to bf16 during LDS staging; W: pre-converted
// transposed bf16 table Wt[c][k]. Both stored with 16B-unit XOR swizzle
// (unit ^= row&7) so ds_read_b64 fragment fetches are ~2-way (free).
// Operand layout (16x16x32): lane q=l>>4,r=l&15; elems 0-3 = k 4q+j,
// elems 4-7 = k 16+4q+j. C/D: col=l&15, row=4q+reg (m89-verified).
// In-place safe (h==out): block reads its own 128 rows before writing them.
// ===========================================================================
template<bool IND>
__global__ __launch_bounds__(256, 2) void apply_k(const float* __restrict__ agg,
                                                  const float* __restrict__ h,
                                                  const int* __restrict__ nid,
                                                  const short* __restrict__ Wt,  // [DD][DD] bf16 swizzled
                                                  float* __restrict__ out) {
    __shared__ short Ash[DD * DD];   // 32 KB bf16, [row][k] swizzled
    __shared__ short Wsh[DD * DD];   // 32 KB bf16, [col][k] swizzled

    const int tid = threadIdx.x;
    const long n0 = (long)blockIdx.x * 128;

    // ---- stage W: linear 32 KB copy (already swizzled in global) ----
    {
        const float4* wsrc = (const float4*)Wt;
        float4*       wdst = (float4*)Wsh;
        #pragma unroll
        for (int i = 0; i < 8; ++i) wdst[tid + i * 256] = wsrc[tid + i * 256];
    }
    // ---- stage A: row r = tid>>1, k-half hf = tid&1; f32 -> bf16 ----
    {
        const int r  = tid >> 1;
        const int hf = tid & 1;
        long srow = n0 + r;
        if (srow >= NN) srow = NN - 1;            // clamp (writes guarded)
        const float* hrow = h + (size_t)(IND ? nid[srow] : (int)srow) * DD + hf * 64;
        short* arow = Ash + r * DD;
        #pragma unroll
        for (int uu = 0; uu < 8; ++uu) {
            int u = hf * 8 + uu;
            float4 f0 = *(const float4*)(hrow + uu * 8);
            float4 f1 = *(const float4*)(hrow + uu * 8 + 4);
            short8 v;
            v[0] = f2bf(f0.x); v[1] = f2bf(f0.y); v[2] = f2bf(f0.z); v[3] = f2bf(f0.w);
            v[4] = f2bf(f1.x); v[5] = f2bf(f1.y); v[6] = f2bf(f1.z); v[7] = f2bf(f1.w);
            *(short8*)(arow + ((u ^ (r & 7)) << 3)) = v;
        }
    }
    __syncthreads();

    const int wv  = tid >> 6;
    const int wm  = wv >> 1;          // wave row 0..1 (64 rows each)
    const int wn  = wv & 1;           // wave col 0..1 (64 cols each)
    const int l16 = tid & 15;
    const int q   = (tid & 63) >> 4;

    f32x4 acc[4][4];
    #pragma unroll
    for (int mt = 0; mt < 4; ++mt)
        #pragma unroll
        for (int nt = 0; nt < 4; ++nt) acc[mt][nt] = (f32x4){0.f, 0.f, 0.f, 0.f};

    union Frag { uint2 u2[2]; short8 s8; };

    #pragma unroll
    for (int ks = 0; ks < 4; ++ks) {
        const int ua   = ks * 4 + (q >> 1);       // unit of k = 32ks + 4q
        const int off8 = 4 * (q & 1);             // elem offset within unit
        short8 af[4], bf[4];
        #pragma unroll
        for (int mt = 0; mt < 4; ++mt) {
            int r = wm * 64 + mt * 16 + l16;
            const short* base = Ash + r * DD;
            Frag fr;
            fr.u2[0] = *(const uint2*)(base + ((ua       ^ (r & 7)) << 3) + off8);
            fr.u2[1] = *(const uint2*)(base + (((ua + 2) ^ (r & 7)) << 3) + off8);
            af[mt] = fr.s8;
        }
        #pragma unroll
        for (int nt = 0; nt < 4; ++nt) {
            int c = wn * 64 + nt * 16 + l16;
            const short* base = Wsh + c * DD;
            Frag fr;
            fr.u2[0] = *(const uint2*)(base + ((ua       ^ (c & 7)) << 3) + off8);
            fr.u2[1] = *(const uint2*)(base + (((ua + 2) ^ (c & 7)) << 3) + off8);
            bf[nt] = fr.s8;
        }
        #pragma unroll
        for (int mt = 0; mt < 4; ++mt)
            #pragma unroll
            for (int nt = 0; nt < 4; ++nt)
                acc[mt][nt] = __builtin_amdgcn_mfma_f32_16x16x32_bf16(
                                  af[mt], bf[nt], acc[mt][nt], 0, 0, 0);
    }

    // ---- epilogue: rrelu(agg + acc) -> out ----
    #pragma unroll
    for (int mt = 0; mt < 4; ++mt) {
        #pragma unroll
        for (int i = 0; i < 4; ++i) {
            long nrow = n0 + wm * 64 + mt * 16 + 4 * q + i;
            if (nrow < NN) {
                #pragma unroll
                for (int nt = 0; nt < 4; ++nt) {
                    int c = wn * 64 + nt * 16 + l16;
                    float v = agg[nrow * DD + c] + acc[mt][nt][i];
                    v = (v >= 0.f) ? v : v * SLOPE;
                    out[nrow * DD + c] = v;
                }
            }
        }
    }
}

extern "C" void kernel_launch(void* const* d_in, const int* in_sizes, int n_in,
                              void* d_out, int out_size, void* d_ws, size_t ws_size,
                              hipStream_t stream) {
    const float* ent_embeds  = (const float*)d_in[0];
    // d_in[1] = rel_embeds (unused by the layer)
    const float* weight      = (const float*)d_in[2];   // [L, R, 256]
    const float* loop_weight = (const float*)d_in[3];   // [L, 128, 128]
    const float* norm        = (const float*)d_in[4];   // [N, 1]
    const int*   node_id     = (const int*)d_in[5];
    const int*   edge_type   = (const int*)d_in[6];
    const int*   src         = (const int*)d_in[7];
    const int*   dst         = (const int*)d_in[8];
    float*       out         = (float*)d_out;

    // Workspace layout (~56.5 MB total)
    float* aggbuf = (float*)d_ws;                               // N*D f32 = 51.2 MB
    int*   cnt    = (int*)(aggbuf + (size_t)NN * DD);           // NN
    int*   off    = cnt + NN;                                   // NN+1
    int*   cursor = off + NN + 1;                               // NN
    int*   bsum   = cursor + NN;                                // 512
    int*   epack0 = bsum + 512;                                 // NE (layer-0 rows)
    int*   epack1 = epack0 + NE;                                // NE (layer-1 rows)
    short* wt     = (short*)(epack1 + NE);                      // 2*DD*DD bf16 = 64 KB

    const int NB_E = (NE + 255) / 256;
    const int NB_N = (NN + 255) / 256;

    // ---- one-time prep: CSR build + W bf16 transpose/swizzle ----
    hipMemsetAsync(cnt, 0, (size_t)NN * sizeof(int), stream);
    wprep_k<<<16,   256, 0, stream>>>(loop_weight, wt);
    hist_k <<<NB_E, 256, 0, stream>>>(dst, cnt);
    scan1_k<<<NB_N, 256, 0, stream>>>(cnt, off, bsum);
    scan2_k<<<1,    512, 0, stream>>>(bsum, NB_N);
    scan3_k<<<NB_N, 256, 0, stream>>>(off, bsum, cursor);
    scat_k <<<NB_E, 256, 0, stream>>>(src, edge_type, dst, node_id, cursor, epack0, epack1);

    const int AGG_BLOCKS = (NN * 64) / 256;    // one wave per node
    const int APL_BLOCKS = (NN + 127) / 128;   // 128 rows per block

    // ---- layer 0: h0 rows pre-resolved into epack0 ----
    agg_k        <<<AGG_BLOCKS, 256, 0, stream>>>(ent_embeds, off, epack0,
                                                  weight, norm, aggbuf);
    apply_k<true><<<APL_BLOCKS, 256, 0, stream>>>(aggbuf, ent_embeds, node_id,
                                                  wt, out);

    // ---- layer 1: h1 lives in d_out; apply runs in-place ----
    agg_k         <<<AGG_BLOCKS, 256, 0, stream>>>(out, off, epack1,
                                                   weight + (size_t)RR * 256, norm, aggbuf);
    apply_k<false><<<APL_BLOCKS, 256, 0, stream>>>(aggbuf, out, nullptr,
                                                   wt + (size_t)DD * DD, out);
}

// Round 7
// 236.455 us; speedup vs baseline: 4.7183x; 1.0593x over previous
//
#include <hip/hip_runtime.h>
#include <hip/hip_bf16.h>

// Problem constants (match reference)
#define NN 100000      // nodes
#define NE 500000      // edges
#define DD 128         // h_dim
#define RR 230         // relation types
// F.rrelu eval-mode slope = (1/8 + 1/3)/2
#define SLOPE 0.2291666666666666667f

typedef __attribute__((ext_vector_type(8))) short short8;
typedef __attribute__((ext_vector_type(4))) float f32x4;

__device__ __forceinline__ short f2bf(float f) {   // RNE f32 -> bf16 bits
    unsigned u = __float_as_uint(f);
    u += 0x7fffu + ((u >> 16) & 1u);
    return (short)(u >> 16);
}
__device__ __forceinline__ float bf2f_lo(unsigned p) { return __uint_as_float(p << 16); }
__device__ __forceinline__ float bf2f_hi(unsigned p) { return __uint_as_float(p & 0xFFFF0000u); }

// ===========================================================================
// hprep: hb[n][:] = bf16(ent_embeds[node_id[n]][:])  (16 threads per row)
// ===========================================================================
__global__ __launch_bounds__(256) void hprep_k(const float* __restrict__ ent,
                                               const int* __restrict__ nid,
                                               unsigned short* __restrict__ hb) {
    int gid = blockIdx.x * 256 + threadIdx.x;
    if (gid >= NN * 16) return;
    int n = gid >> 4;
    int u = gid & 15;
    const float* srcp = ent + (size_t)nid[n] * DD + u * 8;
    float4 f0 = *(const float4*)srcp;
    float4 f1 = *(const float4*)(srcp + 4);
    short8 v;
    v[0] = f2bf(f0.x); v[1] = f2bf(f0.y); v[2] = f2bf(f0.z); v[3] = f2bf(f0.w);
    v[4] = f2bf(f1.x); v[5] = f2bf(f1.y); v[6] = f2bf(f1.z); v[7] = f2bf(f1.w);
    *(short8*)(hb + (size_t)n * DD + u * 8) = v;
}

// ===========================================================================
// CSR-by-dst build: histogram -> 2-level exclusive scan -> scatter
// epack[pos] = (src << 8) | type   (both layers index the local hb table)
// ===========================================================================
__global__ __launch_bounds__(256) void hist_k(const int* __restrict__ dst,
                                              int* __restrict__ cnt) {
    int e = blockIdx.x * 256 + threadIdx.x;
    if (e >= NE) return;
    atomicAdd(&cnt[dst[e]], 1);
}

__global__ __launch_bounds__(256) void scan1_k(const int* __restrict__ cnt,
                                               int* __restrict__ off,
                                               int* __restrict__ bsum) {
    __shared__ int sh[256];
    int i = blockIdx.x * 256 + threadIdx.x;
    int v = (i < NN) ? cnt[i] : 0;
    sh[threadIdx.x] = v;
    __syncthreads();
    for (int d = 1; d < 256; d <<= 1) {
        int t = (threadIdx.x >= d) ? sh[threadIdx.x - d] : 0;
        __syncthreads();
        sh[threadIdx.x] += t;
        __syncthreads();
    }
    if (i < NN) off[i] = sh[threadIdx.x] - v;          // exclusive
    if (threadIdx.x == 255) bsum[blockIdx.x] = sh[255];
}

__global__ __launch_bounds__(512) void scan2_k(int* __restrict__ bsum, int nb) {
    __shared__ int sh[512];
    int v = (threadIdx.x < nb) ? bsum[threadIdx.x] : 0;
    sh[threadIdx.x] = v;
    __syncthreads();
    for (int d = 1; d < 512; d <<= 1) {
        int t = (threadIdx.x >= d) ? sh[threadIdx.x - d] : 0;
        __syncthreads();
        sh[threadIdx.x] += t;
        __syncthreads();
    }
    if (threadIdx.x < nb) bsum[threadIdx.x] = sh[threadIdx.x] - v;  // exclusive
}

__global__ __launch_bounds__(256) void scan3_k(int* __restrict__ off,
                                               const int* __restrict__ bsum,
                                               int* __restrict__ cursor) {
    int i = blockIdx.x * 256 + threadIdx.x;
    if (i < NN) {
        int o = off[i] + bsum[blockIdx.x];
        off[i] = o;
        cursor[i] = o;
    }
    if (i == 0) off[NN] = NE;
}

__global__ __launch_bounds__(256) void scat_k(const int* __restrict__ src,
                                              const int* __restrict__ et,
                                              const int* __restrict__ dst,
                                              int* __restrict__ cursor,
                                              int* __restrict__ epack) {
    int e = blockIdx.x * 256 + threadIdx.x;
    if (e >= NE) return;
    int pos = atomicAdd(&cursor[dst[e]], 1);
    epack[pos] = (src[e] << 8) | et[e];
}

// ===========================================================================
// wprep: loop_weight[l][k][c] f32 -> Wt[l][c][k] bf16, XOR-swizzled on
// 8-elem (16B) units: phys unit = u ^ (c&7).
// ===========================================================================
__global__ __launch_bounds__(256) void wprep_k(const float* __restrict__ lw,
                                               short* __restrict__ wt) {
    int gid = blockIdx.x * 256 + threadIdx.x;
    if (gid >= 2 * DD * 16) return;
    int l   = gid >> 11;
    int rem = gid & 2047;
    int c   = rem >> 4;
    int u   = rem & 15;
    const float* wsrc = lw + l * DD * DD + c;   // stride DD over k
    short8 v;
    #pragma unroll
    for (int j = 0; j < 8; ++j) v[j] = f2bf(wsrc[(u * 8 + j) * DD]);
    *(short8*)(wt + (size_t)l * DD * DD + c * DD + ((u ^ (c & 7)) << 3)) = v;
}

// ===========================================================================
// Aggregate: one wave per dst node. 32 lanes per edge (lane covers 4 dims =
// 2 basis blocks), half-waves process interleaved edges. h rows are bf16
// (256 B/row) -> half the gather traffic of f32.
// ===========================================================================
__global__ __launch_bounds__(256) void agg_k(const unsigned short* __restrict__ hb,
                                             const int* __restrict__ off,
                                             const int* __restrict__ epack,
                                             const float* __restrict__ wl,   // [R,256] this layer
                                             const float* __restrict__ norm,
                                             float* __restrict__ agg) {
    int n    = (blockIdx.x * 256 + threadIdx.x) >> 6;
    int lane = threadIdx.x & 63;
    int hl   = lane & 31;        // dim group: dims 4hl..4hl+3 (blocks 2hl, 2hl+1)
    int h2   = lane >> 5;        // half: handles edges base+2j+h2
    if (n >= NN) return;
    int e0 = off[n];
    int m  = off[n + 1] - e0;
    float a0 = 0.f, a1 = 0.f, a2 = 0.f, a3 = 0.f;

    for (int base = 0; base < m; base += 64) {
        int cnt = m - base;
        if (cnt > 64) cnt = 64;
        int pv = epack[e0 + base + ((lane < cnt) ? lane : cnt - 1)];

        for (int j = 0; j < cnt; j += 8) {
            int i0 = j + 0 + h2, i1 = j + 2 + h2, i2 = j + 4 + h2, i3 = j + 6 + h2;
            int p0 = __shfl(pv, (i0 < cnt) ? i0 : cnt - 1);
            int p1 = __shfl(pv, (i1 < cnt) ? i1 : cnt - 1);
            int p2 = __shfl(pv, (i2 < cnt) ? i2 : cnt - 1);
            int p3 = __shfl(pv, (i3 < cnt) ? i3 : cnt - 1);
            float s0 = (i0 < cnt) ? 1.f : 0.f;
            float s1 = (i1 < cnt) ? 1.f : 0.f;
            float s2 = (i2 < cnt) ? 1.f : 0.f;
            float s3 = (i3 < cnt) ? 1.f : 0.f;
            uint2 xr0 = *(const uint2*)(hb + (size_t)(p0 >> 8) * DD + hl * 4);
            uint2 xr1 = *(const uint2*)(hb + (size_t)(p1 >> 8) * DD + hl * 4);
            uint2 xr2 = *(const uint2*)(hb + (size_t)(p2 >> 8) * DD + hl * 4);
            uint2 xr3 = *(const uint2*)(hb + (size_t)(p3 >> 8) * DD + hl * 4);
            const float* q0 = wl + (size_t)(p0 & 255) * 256 + hl * 8;
            const float* q1 = wl + (size_t)(p1 & 255) * 256 + hl * 8;
            const float* q2 = wl + (size_t)(p2 & 255) * 256 + hl * 8;
            const float* q3 = wl + (size_t)(p3 & 255) * 256 + hl * 8;
            float4 wa0 = *(const float4*)q0, wb0 = *(const float4*)(q0 + 4);
            float4 wa1 = *(const float4*)q1, wb1 = *(const float4*)(q1 + 4);
            float4 wa2 = *(const float4*)q2, wb2 = *(const float4*)(q2 + 4);
            float4 wa3 = *(const float4*)q3, wb3 = *(const float4*)(q3 + 4);
            float4 x0 = make_float4(bf2f_lo(xr0.x) * s0, bf2f_hi(xr0.x) * s0,
                                    bf2f_lo(xr0.y) * s0, bf2f_hi(xr0.y) * s0);
            float4 x1 = make_float4(bf2f_lo(xr1.x) * s1, bf2f_hi(xr1.x) * s1,
                                    bf2f_lo(xr1.y) * s1, bf2f_hi(xr1.y) * s1);
            float4 x2 = make_float4(bf2f_lo(xr2.x) * s2, bf2f_hi(xr2.x) * s2,
                                    bf2f_lo(xr2.y) * s2, bf2f_hi(xr2.y) * s2);
            float4 x3 = make_float4(bf2f_lo(xr3.x) * s3, bf2f_hi(xr3.x) * s3,
                                    bf2f_lo(xr3.y) * s3, bf2f_hi(xr3.y) * s3);
            // block 2hl: out(4hl,4hl+1) from (x.x,x.y); block 2hl+1: out(4hl+2,4hl+3) from (x.z,x.w)
            a0 = fmaf(x0.x, wa0.x, fmaf(x0.y, wa0.z, a0));
            a1 = fmaf(x0.x, wa0.y, fmaf(x0.y, wa0.w, a1));
            a2 = fmaf(x0.z, wb0.x, fmaf(x0.w, wb0.z, a2));
            a3 = fmaf(x0.z, wb0.y, fmaf(x0.w, wb0.w, a3));
            a0 = fmaf(x1.x, wa1.x, fmaf(x1.y, wa1.z, a0));
            a1 = fmaf(x1.x, wa1.y, fmaf(x1.y, wa1.w, a1));
            a2 = fmaf(x1.z, wb1.x, fmaf(x1.w, wb1.z, a2));
            a3 = fmaf(x1.z, wb1.y, fmaf(x1.w, wb1.w, a3));
            a0 = fmaf(x2.x, wa2.x, fmaf(x2.y, wa2.z, a0));
            a1 = fmaf(x2.x, wa2.y, fmaf(x2.y, wa2.w, a1));
            a2 = fmaf(x2.z, wb2.x, fmaf(x2.w, wb2.z, a2));
            a3 = fmaf(x2.z, wb2.y, fmaf(x2.w, wb2.w, a3));
            a0 = fmaf(x3.x, wa3.x, fmaf(x3.y, wa3.z, a0));
            a1 = fmaf(x3.x, wa3.y, fmaf(x3.y, wa3.w, a1));
            a2 = fmaf(x3.z, wb3.x, fmaf(x3.w, wb3.z, a2));
            a3 = fmaf(x3.z, wb3.y, fmaf(x3.w, wb3.w, a3));
        }
    }
    a0 += __shfl_xor(a0, 32);
    a1 += __shfl_xor(a1, 32);
    a2 += __shfl_xor(a2, 32);
    a3 += __shfl_xor(a3, 32);
    if (h2 == 0) {
        float nv = norm[n];
        *(float4*)(agg + (size_t)n * DD + hl * 4) =
            make_float4(a0 * nv, a1 * nv, a2 * nv, a3 * nv);
    }
}

// ===========================================================================
// Apply: h_next[n,:] = rrelu( agg[n,:] + h[n,:] @ W )  via bf16 MFMA 16x16x32.
// A staged from the bf16 h table (pure 16B copies); W from pre-swizzled Wt.
// WRITE_BF16=1: write bf16 h_next in-place into hb (row-local => safe).
// WRITE_BF16=0: write f32 d_out.
// ===========================================================================
template<int WRITE_BF16>
__global__ __launch_bounds__(256, 2) void apply_k(const float* __restrict__ agg,
                                                  const unsigned short* __restrict__ hb,
                                                  const short* __restrict__ Wt,
                                                  float* __restrict__ outf,
                                                  unsigned short* __restrict__ outb) {
    __shared__ short Ash[DD * DD];   // 32 KB bf16, [row][k] swizzled
    __shared__ short Wsh[DD * DD];   // 32 KB bf16, [col][k] swizzled

    const int tid = threadIdx.x;
    const long n0 = (long)blockIdx.x * 128;

    // ---- stage W: linear 32 KB copy (already swizzled in global) ----
    {
        const float4* wsrc = (const float4*)Wt;
        float4*       wdst = (float4*)Wsh;
        #pragma unroll
        for (int i = 0; i < 8; ++i) wdst[tid + i * 256] = wsrc[tid + i * 256];
    }
    // ---- stage A: row r = tid>>1, k-half hf = tid&1 (16B-unit copies) ----
    {
        const int r  = tid >> 1;
        const int hf = tid & 1;
        long srow = n0 + r;
        if (srow >= NN) srow = NN - 1;            // clamp (writes guarded)
        const unsigned short* hrow = hb + (size_t)srow * DD + hf * 64;
        short* arow = Ash + r * DD;
        #pragma unroll
        for (int uu = 0; uu < 8; ++uu) {
            int u = hf * 8 + uu;
            short8 v = *(const short8*)(hrow + uu * 8);
            *(short8*)(arow + ((u ^ (r & 7)) << 3)) = v;
        }
    }
    __syncthreads();

    const int wv  = tid >> 6;
    const int wm  = wv >> 1;          // wave row 0..1 (64 rows each)
    const int wn  = wv & 1;           // wave col 0..1 (64 cols each)
    const int l16 = tid & 15;
    const int q   = (tid & 63) >> 4;

    f32x4 acc[4][4];
    #pragma unroll
    for (int mt = 0; mt < 4; ++mt)
        #pragma unroll
        for (int nt = 0; nt < 4; ++nt) acc[mt][nt] = (f32x4){0.f, 0.f, 0.f, 0.f};

    union Frag { uint2 u2[2]; short8 s8; };

    #pragma unroll
    for (int ks = 0; ks < 4; ++ks) {
        const int ua   = ks * 4 + (q >> 1);       // unit of k = 32ks + 4q
        const int off8 = 4 * (q & 1);             // elem offset within unit
        short8 af[4], bf[4];
        #pragma unroll
        for (int mt = 0; mt < 4; ++mt) {
            int r = wm * 64 + mt * 16 + l16;
            const short* base = Ash + r * DD;
            Frag fr;
            fr.u2[0] = *(const uint2*)(base + ((ua       ^ (r & 7)) << 3) + off8);
            fr.u2[1] = *(const uint2*)(base + (((ua + 2) ^ (r & 7)) << 3) + off8);
            af[mt] = fr.s8;
        }
        #pragma unroll
        for (int nt = 0; nt < 4; ++nt) {
            int c = wn * 64 + nt * 16 + l16;
            const short* base = Wsh + c * DD;
            Frag fr;
            fr.u2[0] = *(const uint2*)(base + ((ua       ^ (c & 7)) << 3) + off8);
            fr.u2[1] = *(const uint2*)(base + (((ua + 2) ^ (c & 7)) << 3) + off8);
            bf[nt] = fr.s8;
        }
        #pragma unroll
        for (int mt = 0; mt < 4; ++mt)
            #pragma unroll
            for (int nt = 0; nt < 4; ++nt)
                acc[mt][nt] = __builtin_amdgcn_mfma_f32_16x16x32_bf16(
                                  af[mt], bf[nt], acc[mt][nt], 0, 0, 0);
    }

    // ---- epilogue: rrelu(agg + acc) ----
    #pragma unroll
    for (int mt = 0; mt < 4; ++mt) {
        #pragma unroll
        for (int i = 0; i < 4; ++i) {
            long nrow = n0 + wm * 64 + mt * 16 + 4 * q + i;
            if (nrow < NN) {
                #pragma unroll
                for (int nt = 0; nt < 4; ++nt) {
                    int c = wn * 64 + nt * 16 + l16;
                    float v = agg[nrow * DD + c] + acc[mt][nt][i];
                    v = (v >= 0.f) ? v : v * SLOPE;
                    if (WRITE_BF16) outb[nrow * DD + c] = (unsigned short)f2bf(v);
                    else            outf[nrow * DD + c] = v;
                }
            }
        }
    }
}

extern "C" void kernel_launch(void* const* d_in, const int* in_sizes, int n_in,
                              void* d_out, int out_size, void* d_ws, size_t ws_size,
                              hipStream_t stream) {
    const float* ent_embeds  = (const float*)d_in[0];
    // d_in[1] = rel_embeds (unused by the layer)
    const float* weight      = (const float*)d_in[2];   // [L, R, 256]
    const float* loop_weight = (const float*)d_in[3];   // [L, 128, 128]
    const float* norm        = (const float*)d_in[4];   // [N, 1]
    const int*   node_id     = (const int*)d_in[5];
    const int*   edge_type   = (const int*)d_in[6];
    const int*   src         = (const int*)d_in[7];
    const int*   dst         = (const int*)d_in[8];
    float*       out         = (float*)d_out;

    // Workspace layout (~80 MB total)
    float*          aggbuf = (float*)d_ws;                        // N*D f32  = 51.2 MB
    unsigned short* hb     = (unsigned short*)(aggbuf + (size_t)NN * DD);  // N*D bf16 = 25.6 MB
    int*   cnt    = (int*)(hb + (size_t)NN * DD);                 // NN
    int*   off    = cnt + NN;                                     // NN+1
    int*   cursor = off + NN + 1;                                 // NN
    int*   bsum   = cursor + NN;                                  // 512
    int*   epack  = bsum + 512;                                   // NE
    short* wt     = (short*)(epack + NE);                         // 2*DD*DD bf16 = 64 KB

    const int NB_E = (NE + 255) / 256;
    const int NB_N = (NN + 255) / 256;

    // ---- one-time prep ----
    hipMemsetAsync(cnt, 0, (size_t)NN * sizeof(int), stream);
    wprep_k<<<16,   256, 0, stream>>>(loop_weight, wt);
    hprep_k<<<(NN * 16 + 255) / 256, 256, 0, stream>>>(ent_embeds, node_id, hb);
    hist_k <<<NB_E, 256, 0, stream>>>(dst, cnt);
    scan1_k<<<NB_N, 256, 0, stream>>>(cnt, off, bsum);
    scan2_k<<<1,    512, 0, stream>>>(bsum, NB_N);
    scan3_k<<<NB_N, 256, 0, stream>>>(off, bsum, cursor);
    scat_k <<<NB_E, 256, 0, stream>>>(src, edge_type, dst, cursor, epack);

    const int AGG_BLOCKS = (NN * 64) / 256;    // one wave per node
    const int APL_BLOCKS = (NN + 127) / 128;   // 128 rows per block

    // ---- layer 0: agg from hb(=h0), apply writes h1 bf16 in-place into hb ----
    agg_k     <<<AGG_BLOCKS, 256, 0, stream>>>(hb, off, epack, weight, norm, aggbuf);
    apply_k<1><<<APL_BLOCKS, 256, 0, stream>>>(aggbuf, hb, wt, nullptr, hb);

    // ---- layer 1: agg from hb(=h1), apply writes final f32 out ----
    agg_k     <<<AGG_BLOCKS, 256, 0, stream>>>(hb, off, epack,
                                               weight + (size_t)RR * 256, norm, aggbuf);
    apply_k<0><<<APL_BLOCKS, 256, 0, stream>>>(aggbuf, hb, wt + (size_t)DD * DD, out, nullptr);
}

// Round 8
// 212.471 us; speedup vs baseline: 5.2510x; 1.1129x over previous
//
#include <hip/hip_runtime.h>
#include <hip/hip_bf16.h>

// Problem constants (match reference)
#define NN 100000      // nodes
#define NE 500000      // edges
#define DD 128         // h_dim
#define RR 230         // relation types
// F.rrelu eval-mode slope = (1/8 + 1/3)/2
#define SLOPE 0.2291666666666666667f

typedef __attribute__((ext_vector_type(8))) short short8;
typedef __attribute__((ext_vector_type(4))) float f32x4;

__device__ __forceinline__ short f2bf(float f) {   // RNE f32 -> bf16 bits
    unsigned u = __float_as_uint(f);
    u += 0x7fffu + ((u >> 16) & 1u);
    return (short)(u >> 16);
}
__device__ __forceinline__ unsigned pkbf(float lo, float hi) {
    return (unsigned)(unsigned short)f2bf(lo) | ((unsigned)(unsigned short)f2bf(hi) << 16);
}

// dot2: acc += x.lo*w.lo + x.hi*w.hi   (bf16 pairs packed in uint)
#if defined(__has_builtin)
#if __has_builtin(__builtin_amdgcn_fdot2_f32_bf16)
#define HAS_DOT2 1
#endif
#endif
__device__ __forceinline__ void dot2acc(float& acc, unsigned x, unsigned w) {
#ifdef HAS_DOT2
    typedef __attribute__((ext_vector_type(2))) __bf16 bf16x2;
    acc = __builtin_amdgcn_fdot2_f32_bf16(__builtin_bit_cast(bf16x2, x),
                                          __builtin_bit_cast(bf16x2, w), acc, false);
#else
    acc = fmaf(__uint_as_float(x << 16),        __uint_as_float(w << 16),
          fmaf(__uint_as_float(x & 0xFFFF0000u), __uint_as_float(w & 0xFFFF0000u), acc));
#endif
}

// ===========================================================================
// hprep: hb[n][:] = bf16(ent_embeds[node_id[n]][:]); row NN = zeros (demask row)
// ===========================================================================
__global__ __launch_bounds__(256) void hprep_k(const float* __restrict__ ent,
                                               const int* __restrict__ nid,
                                               unsigned short* __restrict__ hb) {
    int gid = blockIdx.x * 256 + threadIdx.x;
    if (gid >= (NN + 1) * 16) return;
    int n = gid >> 4;
    int u = gid & 15;
    short8 v = {0, 0, 0, 0, 0, 0, 0, 0};
    if (n < NN) {
        const float* srcp = ent + (size_t)nid[n] * DD + u * 8;
        float4 f0 = *(const float4*)srcp;
        float4 f1 = *(const float4*)(srcp + 4);
        v[0] = f2bf(f0.x); v[1] = f2bf(f0.y); v[2] = f2bf(f0.z); v[3] = f2bf(f0.w);
        v[4] = f2bf(f1.x); v[5] = f2bf(f1.y); v[6] = f2bf(f1.z); v[7] = f2bf(f1.w);
    }
    *(short8*)(hb + (size_t)n * DD + u * 8) = v;
}

// ===========================================================================
// CSR-by-dst build: histogram -> 2-level exclusive scan -> scatter
// epack[pos] = (src << 8) | type
// ===========================================================================
__global__ __launch_bounds__(256) void hist_k(const int* __restrict__ dst,
                                              int* __restrict__ cnt) {
    int e = blockIdx.x * 256 + threadIdx.x;
    if (e >= NE) return;
    atomicAdd(&cnt[dst[e]], 1);
}

__global__ __launch_bounds__(256) void scan1_k(const int* __restrict__ cnt,
                                               int* __restrict__ off,
                                               int* __restrict__ bsum) {
    __shared__ int sh[256];
    int i = blockIdx.x * 256 + threadIdx.x;
    int v = (i < NN) ? cnt[i] : 0;
    sh[threadIdx.x] = v;
    __syncthreads();
    for (int d = 1; d < 256; d <<= 1) {
        int t = (threadIdx.x >= d) ? sh[threadIdx.x - d] : 0;
        __syncthreads();
        sh[threadIdx.x] += t;
        __syncthreads();
    }
    if (i < NN) off[i] = sh[threadIdx.x] - v;          // exclusive
    if (threadIdx.x == 255) bsum[blockIdx.x] = sh[255];
}

__global__ __launch_bounds__(512) void scan2_k(int* __restrict__ bsum, int nb) {
    __shared__ int sh[512];
    int v = (threadIdx.x < nb) ? bsum[threadIdx.x] : 0;
    sh[threadIdx.x] = v;
    __syncthreads();
    for (int d = 1; d < 512; d <<= 1) {
        int t = (threadIdx.x >= d) ? sh[threadIdx.x - d] : 0;
        __syncthreads();
        sh[threadIdx.x] += t;
        __syncthreads();
    }
    if (threadIdx.x < nb) bsum[threadIdx.x] = sh[threadIdx.x] - v;  // exclusive
}

__global__ __launch_bounds__(256) void scan3_k(int* __restrict__ off,
                                               const int* __restrict__ bsum,
                                               int* __restrict__ cursor) {
    int i = blockIdx.x * 256 + threadIdx.x;
    if (i < NN) {
        int o = off[i] + bsum[blockIdx.x];
        off[i] = o;
        cursor[i] = o;
    }
    if (i == 0) off[NN] = NE;
}

__global__ __launch_bounds__(256) void scat_k(const int* __restrict__ src,
                                              const int* __restrict__ et,
                                              const int* __restrict__ dst,
                                              int* __restrict__ cursor,
                                              int* __restrict__ epack) {
    int e = blockIdx.x * 256 + threadIdx.x;
    if (e >= NE) return;
    int pos = atomicAdd(&cursor[dst[e]], 1);
    epack[pos] = (src[e] << 8) | et[e];
}

// ===========================================================================
// wbprep: relation weights -> packed bf16 pair table.
// wb[l][t][hl*4 + {0..3}] (uints). Pair q for output o of block b:
// (w[b*4+o], w[b*4+2+o]) = (i0,o),(i1,o) -- feeds v_dot2 with x pair (x0,x1).
// ===========================================================================
__global__ __launch_bounds__(256) void wbprep_k(const float* __restrict__ weight,
                                                unsigned* __restrict__ wb) {
    int gid = blockIdx.x * 256 + threadIdx.x;
    if (gid >= 2 * RR * 32) return;
    int lt = gid >> 5;           // l*RR + t
    int hl = gid & 31;
    const float* wsrc = weight + (size_t)lt * 256 + hl * 8;   // blocks 2hl, 2hl+1
    float4 f0 = *(const float4*)wsrc;        // b0: (i0o0,i0o1,i1o0,i1o1)
    float4 f1 = *(const float4*)(wsrc + 4);  // b1
    uint4 v;
    v.x = pkbf(f0.x, f0.z);   // b0, o=0
    v.y = pkbf(f0.y, f0.w);   // b0, o=1
    v.z = pkbf(f1.x, f1.z);   // b1, o=0
    v.w = pkbf(f1.y, f1.w);   // b1, o=1
    *(uint4*)(wb + (size_t)lt * 128 + hl * 4) = v;
}

// ===========================================================================
// wprep: loop_weight[l][k][c] f32 -> Wt[l][c][k] bf16, XOR-swizzled on
// 8-elem (16B) units: phys unit = u ^ (c&7).  (MFMA B operand table)
// ===========================================================================
__global__ __launch_bounds__(256) void wprep_k(const float* __restrict__ lw,
                                               short* __restrict__ wt) {
    int gid = blockIdx.x * 256 + threadIdx.x;
    if (gid >= 2 * DD * 16) return;
    int l   = gid >> 11;
    int rem = gid & 2047;
    int c   = rem >> 4;
    int u   = rem & 15;
    const float* wsrc = lw + l * DD * DD + c;   // stride DD over k
    short8 v;
    #pragma unroll
    for (int j = 0; j < 8; ++j) v[j] = f2bf(wsrc[(u * 8 + j) * DD]);
    *(short8*)(wt + (size_t)l * DD * DD + c * DD + ((u ^ (c & 7)) << 3)) = v;
}

// ===========================================================================
// Aggregate: one wave per dst node. 32 lanes per edge (lane covers 4 dims =
// 2 basis blocks), half-waves process interleaved edges. OOB slots read the
// all-zero hb row NN (no masks). Row byte-offset = p & ~255 (pack trick).
// Output agg is bf16.
// ===========================================================================
#define ZP (NN << 8)
__global__ __launch_bounds__(256) void agg_k(const unsigned short* __restrict__ hb,
                                             const int* __restrict__ off,
                                             const int* __restrict__ epack,
                                             const unsigned* __restrict__ wb,  // packed pairs, this layer
                                             const float* __restrict__ norm,
                                             unsigned short* __restrict__ aggb) {
    int n    = (blockIdx.x * 256 + threadIdx.x) >> 6;
    int lane = threadIdx.x & 63;
    int hl   = lane & 31;        // dim group: dims 4hl..4hl+3 (blocks 2hl, 2hl+1)
    int h2   = lane >> 5;        // half: handles edges j+2k+h2
    if (n >= NN) return;
    int e0 = off[n];
    int m  = off[n + 1] - e0;
    float a0 = 0.f, a1 = 0.f, a2 = 0.f, a3 = 0.f;
    const char* hbb = (const char*)hb;
    const char* wbb = (const char*)wb;
    const int hoff = hl * 8;     // byte offset within h row
    const int woff = hl * 16;    // byte offset within packed w row (512 B)

    for (int base = 0; base < m; base += 64) {
        int cnt = m - base;
        if (cnt > 64) cnt = 64;
        int pv = epack[e0 + base + ((lane < cnt) ? lane : 0)];

        for (int j = 0; j < cnt; j += 8) {
            int i0 = j + h2, i1 = j + 2 + h2, i2 = j + 4 + h2, i3 = j + 6 + h2;
            int p0 = (i0 < cnt) ? __shfl(pv, i0) : ZP;
            int p1 = (i1 < cnt) ? __shfl(pv, i1) : ZP;
            int p2 = (i2 < cnt) ? __shfl(pv, i2) : ZP;
            int p3 = (i3 < cnt) ? __shfl(pv, i3) : ZP;
            uint2 x0 = *(const uint2*)(hbb + (p0 & 0xFFFFFF00u) + hoff);
            uint2 x1 = *(const uint2*)(hbb + (p1 & 0xFFFFFF00u) + hoff);
            uint2 x2 = *(const uint2*)(hbb + (p2 & 0xFFFFFF00u) + hoff);
            uint2 x3 = *(const uint2*)(hbb + (p3 & 0xFFFFFF00u) + hoff);
            uint4 w0 = *(const uint4*)(wbb + ((p0 & 255) << 9) + woff);
            uint4 w1 = *(const uint4*)(wbb + ((p1 & 255) << 9) + woff);
            uint4 w2 = *(const uint4*)(wbb + ((p2 & 255) << 9) + woff);
            uint4 w3 = *(const uint4*)(wbb + ((p3 & 255) << 9) + woff);
            dot2acc(a0, x0.x, w0.x); dot2acc(a1, x0.x, w0.y);
            dot2acc(a2, x0.y, w0.z); dot2acc(a3, x0.y, w0.w);
            dot2acc(a0, x1.x, w1.x); dot2acc(a1, x1.x, w1.y);
            dot2acc(a2, x1.y, w1.z); dot2acc(a3, x1.y, w1.w);
            dot2acc(a0, x2.x, w2.x); dot2acc(a1, x2.x, w2.y);
            dot2acc(a2, x2.y, w2.z); dot2acc(a3, x2.y, w2.w);
            dot2acc(a0, x3.x, w3.x); dot2acc(a1, x3.x, w3.y);
            dot2acc(a2, x3.y, w3.z); dot2acc(a3, x3.y, w3.w);
        }
    }
    a0 += __shfl_xor(a0, 32);
    a1 += __shfl_xor(a1, 32);
    a2 += __shfl_xor(a2, 32);
    a3 += __shfl_xor(a3, 32);
    if (h2 == 0) {
        float nv = norm[n];
        uint2 pk;
        pk.x = pkbf(a0 * nv, a1 * nv);
        pk.y = pkbf(a2 * nv, a3 * nv);
        *(uint2*)(aggb + (size_t)n * DD + hl * 4) = pk;
    }
}

// ===========================================================================
// Apply: h_next[n,:] = rrelu( agg[n,:] + h[n,:] @ W )  via bf16 MFMA 16x16x32.
// A staged from the bf16 h table (pure 16B copies); W from pre-swizzled Wt.
// agg input is bf16. WRITE_BF16=1: write bf16 h_next in-place into hb
// (row-local => safe). WRITE_BF16=0: write f32 d_out.
// ===========================================================================
template<int WRITE_BF16>
__global__ __launch_bounds__(256, 2) void apply_k(const unsigned short* __restrict__ aggb,
                                                  const unsigned short* __restrict__ hb,
                                                  const short* __restrict__ Wt,
                                                  float* __restrict__ outf,
                                                  unsigned short* __restrict__ outb) {
    __shared__ short Ash[DD * DD];   // 32 KB bf16, [row][k] swizzled
    __shared__ short Wsh[DD * DD];   // 32 KB bf16, [col][k] swizzled

    const int tid = threadIdx.x;
    const long n0 = (long)blockIdx.x * 128;

    // ---- stage W: linear 32 KB copy (already swizzled in global) ----
    {
        const float4* wsrc = (const float4*)Wt;
        float4*       wdst = (float4*)Wsh;
        #pragma unroll
        for (int i = 0; i < 8; ++i) wdst[tid + i * 256] = wsrc[tid + i * 256];
    }
    // ---- stage A: row r = tid>>1, k-half hf = tid&1 (16B-unit copies) ----
    {
        const int r  = tid >> 1;
        const int hf = tid & 1;
        long srow = n0 + r;
        if (srow >= NN) srow = NN - 1;            // clamp (writes guarded)
        const unsigned short* hrow = hb + (size_t)srow * DD + hf * 64;
        short* arow = Ash + r * DD;
        #pragma unroll
        for (int uu = 0; uu < 8; ++uu) {
            int u = hf * 8 + uu;
            short8 v = *(const short8*)(hrow + uu * 8);
            *(short8*)(arow + ((u ^ (r & 7)) << 3)) = v;
        }
    }
    __syncthreads();

    const int wv  = tid >> 6;
    const int wm  = wv >> 1;          // wave row 0..1 (64 rows each)
    const int wn  = wv & 1;           // wave col 0..1 (64 cols each)
    const int l16 = tid & 15;
    const int q   = (tid & 63) >> 4;

    f32x4 acc[4][4];
    #pragma unroll
    for (int mt = 0; mt < 4; ++mt)
        #pragma unroll
        for (int nt = 0; nt < 4; ++nt) acc[mt][nt] = (f32x4){0.f, 0.f, 0.f, 0.f};

    union Frag { uint2 u2[2]; short8 s8; };

    #pragma unroll
    for (int ks = 0; ks < 4; ++ks) {
        const int ua   = ks * 4 + (q >> 1);       // unit of k = 32ks + 4q
        const int off8 = 4 * (q & 1);             // elem offset within unit
        short8 af[4], bf[4];
        #pragma unroll
        for (int mt = 0; mt < 4; ++mt) {
            int r = wm * 64 + mt * 16 + l16;
            const short* base = Ash + r * DD;
            Frag fr;
            fr.u2[0] = *(const uint2*)(base + ((ua       ^ (r & 7)) << 3) + off8);
            fr.u2[1] = *(const uint2*)(base + (((ua + 2) ^ (r & 7)) << 3) + off8);
            af[mt] = fr.s8;
        }
        #pragma unroll
        for (int nt = 0; nt < 4; ++nt) {
            int c = wn * 64 + nt * 16 + l16;
            const short* base = Wsh + c * DD;
            Frag fr;
            fr.u2[0] = *(const uint2*)(base + ((ua       ^ (c & 7)) << 3) + off8);
            fr.u2[1] = *(const uint2*)(base + (((ua + 2) ^ (c & 7)) << 3) + off8);
            bf[nt] = fr.s8;
        }
        #pragma unroll
        for (int mt = 0; mt < 4; ++mt)
            #pragma unroll
            for (int nt = 0; nt < 4; ++nt)
                acc[mt][nt] = __builtin_amdgcn_mfma_f32_16x16x32_bf16(
                                  af[mt], bf[nt], acc[mt][nt], 0, 0, 0);
    }

    // ---- epilogue: rrelu(agg + acc) ----
    #pragma unroll
    for (int mt = 0; mt < 4; ++mt) {
        #pragma unroll
        for (int i = 0; i < 4; ++i) {
            long nrow = n0 + wm * 64 + mt * 16 + 4 * q + i;
            if (nrow < NN) {
                #pragma unroll
                for (int nt = 0; nt < 4; ++nt) {
                    int c = wn * 64 + nt * 16 + l16;
                    float g = __uint_as_float((unsigned)aggb[nrow * DD + c] << 16);
                    float v = g + acc[mt][nt][i];
                    v = (v >= 0.f) ? v : v * SLOPE;
                    if (WRITE_BF16) outb[nrow * DD + c] = (unsigned short)f2bf(v);
                    else            outf[nrow * DD + c] = v;
                }
            }
        }
    }
}

extern "C" void kernel_launch(void* const* d_in, const int* in_sizes, int n_in,
                              void* d_out, int out_size, void* d_ws, size_t ws_size,
                              hipStream_t stream) {
    const float* ent_embeds  = (const float*)d_in[0];
    // d_in[1] = rel_embeds (unused by the layer)
    const float* weight      = (const float*)d_in[2];   // [L, R, 256]
    const float* loop_weight = (const float*)d_in[3];   // [L, 128, 128]
    const float* norm        = (const float*)d_in[4];   // [N, 1]
    const int*   node_id     = (const int*)d_in[5];
    const int*   edge_type   = (const int*)d_in[6];
    const int*   src         = (const int*)d_in[7];
    const int*   dst         = (const int*)d_in[8];
    float*       out         = (float*)d_out;

    // Workspace layout (~54 MB total)
    unsigned short* aggb = (unsigned short*)d_ws;                  // N*D bf16 = 25.6 MB
    unsigned short* hb   = aggb + (size_t)NN * DD;                 // (N+1)*D bf16
    int*   cnt    = (int*)(hb + (size_t)(NN + 1) * DD);            // NN
    int*   off    = cnt + NN;                                      // NN+1
    int*   cursor = off + NN + 1;                                  // NN
    int*   bsum   = cursor + NN;                                   // 512
    int*   epack  = bsum + 512;                                    // NE
    short* wt     = (short*)(epack + NE);                          // 2*DD*DD bf16 = 64 KB
    unsigned* wb  = (unsigned*)(wt + 2 * DD * DD);                 // 2*RR*128 uints = 235 KB

    const int NB_E = (NE + 255) / 256;
    const int NB_N = (NN + 255) / 256;

    // ---- one-time prep ----
    hipMemsetAsync(cnt, 0, (size_t)NN * sizeof(int), stream);
    wprep_k <<<16, 256, 0, stream>>>(loop_weight, wt);
    wbprep_k<<<(2 * RR * 32 + 255) / 256, 256, 0, stream>>>(weight, wb);
    hprep_k <<<((NN + 1) * 16 + 255) / 256, 256, 0, stream>>>(ent_embeds, node_id, hb);
    hist_k  <<<NB_E, 256, 0, stream>>>(dst, cnt);
    scan1_k <<<NB_N, 256, 0, stream>>>(cnt, off, bsum);
    scan2_k <<<1,    512, 0, stream>>>(bsum, NB_N);
    scan3_k <<<NB_N, 256, 0, stream>>>(off, bsum, cursor);
    scat_k  <<<NB_E, 256, 0, stream>>>(src, edge_type, dst, cursor, epack);

    const int AGG_BLOCKS = (NN * 64) / 256;    // one wave per node
    const int APL_BLOCKS = (NN + 127) / 128;   // 128 rows per block

    // ---- layer 0: agg from hb(=h0), apply writes h1 bf16 in-place into hb ----
    agg_k     <<<AGG_BLOCKS, 256, 0, stream>>>(hb, off, epack, wb, norm, aggb);
    apply_k<1><<<APL_BLOCKS, 256, 0, stream>>>(aggb, hb, wt, nullptr, hb);

    // ---- layer 1: agg from hb(=h1), apply writes final f32 out ----
    agg_k     <<<AGG_BLOCKS, 256, 0, stream>>>(hb, off, epack, wb + (size_t)RR * 128,
                                               norm, aggb);
    apply_k<0><<<APL_BLOCKS, 256, 0, stream>>>(aggb, hb, wt + (size_t)DD * DD, out, nullptr);
}

// Round 9
// 203.101 us; speedup vs baseline: 5.4932x; 1.0461x over previous
//
#include <hip/hip_runtime.h>
#include <hip/hip_bf16.h>

// Problem constants (match reference)
#define NN 100000      // nodes
#define NE 500000      // edges
#define DD 128         // h_dim
#define RR 230         // relation types
// F.rrelu eval-mode slope = (1/8 + 1/3)/2
#define SLOPE 0.2291666666666666667f

typedef __attribute__((ext_vector_type(8))) short short8;
typedef __attribute__((ext_vector_type(4))) float f32x4;

__device__ __forceinline__ short f2bf(float f) {   // RNE f32 -> bf16 bits
    unsigned u = __float_as_uint(f);
    u += 0x7fffu + ((u >> 16) & 1u);
    return (short)(u >> 16);
}
__device__ __forceinline__ unsigned pkbf(float lo, float hi) {
    return (unsigned)(unsigned short)f2bf(lo) | ((unsigned)(unsigned short)f2bf(hi) << 16);
}

// dot2: acc += x.lo*w.lo + x.hi*w.hi   (bf16 pairs packed in uint)
#if defined(__has_builtin)
#if __has_builtin(__builtin_amdgcn_fdot2_f32_bf16)
#define HAS_DOT2 1
#endif
#endif
__device__ __forceinline__ void dot2acc(float& acc, unsigned x, unsigned w) {
#ifdef HAS_DOT2
    typedef __attribute__((ext_vector_type(2))) __bf16 bf16x2;
    acc = __builtin_amdgcn_fdot2_f32_bf16(__builtin_bit_cast(bf16x2, x),
                                          __builtin_bit_cast(bf16x2, w), acc, false);
#else
    acc = fmaf(__uint_as_float(x << 16),        __uint_as_float(w << 16),
          fmaf(__uint_as_float(x & 0xFFFF0000u), __uint_as_float(w & 0xFFFF0000u), acc));
#endif
}

// ===========================================================================
// prep_k: fused one-time prep, partitioned by blockIdx:
//   [0,16)       : loop_weight f32 -> Wt bf16 transposed+swizzled (MFMA B)
//   [16,74)      : relation weights -> packed bf16 pair table wb
//   [74,74+6251) : hb[n] = bf16(ent[node_id[n]]); row NN = zeros
// ===========================================================================
#define PREP_WB_B   16
#define PREP_HB_B   74
#define PREP_TOT_B  (74 + ((NN + 1) * 16 + 255) / 256)

__global__ __launch_bounds__(256) void prep_k(const float* __restrict__ lw,
                                              const float* __restrict__ weight,
                                              const float* __restrict__ ent,
                                              const int* __restrict__ nid,
                                              short* __restrict__ wt,
                                              unsigned* __restrict__ wb,
                                              unsigned short* __restrict__ hb) {
    int bid = blockIdx.x;
    if (bid < PREP_WB_B) {
        // ---- wprep: Wt[l][c][k] bf16, 16B-unit swizzle u^(c&7) ----
        int gid = bid * 256 + threadIdx.x;
        if (gid >= 2 * DD * 16) return;
        int l   = gid >> 11;
        int rem = gid & 2047;
        int c   = rem >> 4;
        int u   = rem & 15;
        const float* wsrc = lw + l * DD * DD + c;   // stride DD over k
        short8 v;
        #pragma unroll
        for (int j = 0; j < 8; ++j) v[j] = f2bf(wsrc[(u * 8 + j) * DD]);
        *(short8*)(wt + (size_t)l * DD * DD + c * DD + ((u ^ (c & 7)) << 3)) = v;
    } else if (bid < PREP_HB_B) {
        // ---- wbprep: packed bf16 pairs per (l,t,hl) ----
        int gid = (bid - PREP_WB_B) * 256 + threadIdx.x;
        if (gid >= 2 * RR * 32) return;
        int lt = gid >> 5;           // l*RR + t
        int hl = gid & 31;
        const float* wsrc = weight + (size_t)lt * 256 + hl * 8;   // blocks 2hl, 2hl+1
        float4 f0 = *(const float4*)wsrc;        // b0: (i0o0,i0o1,i1o0,i1o1)
        float4 f1 = *(const float4*)(wsrc + 4);  // b1
        uint4 v;
        v.x = pkbf(f0.x, f0.z);   // b0, o=0
        v.y = pkbf(f0.y, f0.w);   // b0, o=1
        v.z = pkbf(f1.x, f1.z);   // b1, o=0
        v.w = pkbf(f1.y, f1.w);   // b1, o=1
        *(uint4*)(wb + (size_t)lt * 128 + hl * 4) = v;
    } else {
        // ---- hprep: hb[n] = bf16(ent[nid[n]]); row NN = zeros ----
        int gid = (bid - PREP_HB_B) * 256 + threadIdx.x;
        if (gid >= (NN + 1) * 16) return;
        int n = gid >> 4;
        int u = gid & 15;
        short8 v = {0, 0, 0, 0, 0, 0, 0, 0};
        if (n < NN) {
            const float* srcp = ent + (size_t)nid[n] * DD + u * 8;
            float4 f0 = *(const float4*)srcp;
            float4 f1 = *(const float4*)(srcp + 4);
            v[0] = f2bf(f0.x); v[1] = f2bf(f0.y); v[2] = f2bf(f0.z); v[3] = f2bf(f0.w);
            v[4] = f2bf(f1.x); v[5] = f2bf(f1.y); v[6] = f2bf(f1.z); v[7] = f2bf(f1.w);
        }
        *(short8*)(hb + (size_t)n * DD + u * 8) = v;
    }
}

// ===========================================================================
// CSR-by-dst build: histogram -> 2-level exclusive scan -> scatter
// epack[pos] = (src << 8) | type
// ===========================================================================
__global__ __launch_bounds__(256) void hist_k(const int* __restrict__ dst,
                                              int* __restrict__ cnt) {
    int e = blockIdx.x * 256 + threadIdx.x;
    if (e >= NE) return;
    atomicAdd(&cnt[dst[e]], 1);
}

__global__ __launch_bounds__(256) void scan1_k(const int* __restrict__ cnt,
                                               int* __restrict__ off,
                                               int* __restrict__ bsum) {
    __shared__ int sh[256];
    int i = blockIdx.x * 256 + threadIdx.x;
    int v = (i < NN) ? cnt[i] : 0;
    sh[threadIdx.x] = v;
    __syncthreads();
    for (int d = 1; d < 256; d <<= 1) {
        int t = (threadIdx.x >= d) ? sh[threadIdx.x - d] : 0;
        __syncthreads();
        sh[threadIdx.x] += t;
        __syncthreads();
    }
    if (i < NN) off[i] = sh[threadIdx.x] - v;          // exclusive
    if (threadIdx.x == 255) bsum[blockIdx.x] = sh[255];
}

__global__ __launch_bounds__(512) void scan2_k(int* __restrict__ bsum, int nb) {
    __shared__ int sh[512];
    int v = (threadIdx.x < nb) ? bsum[threadIdx.x] : 0;
    sh[threadIdx.x] = v;
    __syncthreads();
    for (int d = 1; d < 512; d <<= 1) {
        int t = (threadIdx.x >= d) ? sh[threadIdx.x - d] : 0;
        __syncthreads();
        sh[threadIdx.x] += t;
        __syncthreads();
    }
    if (threadIdx.x < nb) bsum[threadIdx.x] = sh[threadIdx.x] - v;  // exclusive
}

__global__ __launch_bounds__(256) void scan3_k(int* __restrict__ off,
                                               const int* __restrict__ bsum,
                                               int* __restrict__ cursor) {
    int i = blockIdx.x * 256 + threadIdx.x;
    if (i < NN) {
        int o = off[i] + bsum[blockIdx.x];
        off[i] = o;
        cursor[i] = o;
    }
    if (i == 0) off[NN] = NE;
}

__global__ __launch_bounds__(256) void scat_k(const int* __restrict__ src,
                                              const int* __restrict__ et,
                                              const int* __restrict__ dst,
                                              int* __restrict__ cursor,
                                              int* __restrict__ epack) {
    int e = blockIdx.x * 256 + threadIdx.x;
    if (e >= NE) return;
    int pos = atomicAdd(&cursor[dst[e]], 1);
    epack[pos] = (src[e] << 8) | et[e];
}

// ===========================================================================
// Aggregate: one wave per dst node. 32 lanes per edge (lane covers 4 dims =
// 2 basis blocks), half-waves process interleaved edges. OOB slots read the
// all-zero hb row NN. Row byte-offset = p & ~255 (pack trick).
// deg<=8: single 8-slot group (common case). deg>8: 16 slots/iteration for
// straggler waves (16 gathers in flight). Wave-uniform branch.
// ===========================================================================
#define ZP (NN << 8)
__global__ __launch_bounds__(256) void agg_k(const unsigned short* __restrict__ hb,
                                             const int* __restrict__ off,
                                             const int* __restrict__ epack,
                                             const unsigned* __restrict__ wb,  // packed pairs, this layer
                                             const float* __restrict__ norm,
                                             unsigned short* __restrict__ aggb) {
    int n    = (blockIdx.x * 256 + threadIdx.x) >> 6;
    int lane = threadIdx.x & 63;
    int hl   = lane & 31;        // dim group: dims 4hl..4hl+3 (blocks 2hl, 2hl+1)
    int h2   = lane >> 5;        // half: handles edge slots 2k+h2
    if (n >= NN) return;
    int e0 = off[n];
    int m  = off[n + 1] - e0;
    float nv = norm[n];
    float a0 = 0.f, a1 = 0.f, a2 = 0.f, a3 = 0.f;
    const char* hbb = (const char*)hb;
    const char* wbb = (const char*)wb;
    const int hoff = hl * 8;     // byte offset within h row (256 B)
    const int woff = hl * 16;    // byte offset within packed w row (512 B)

    if (m <= 8) {
        // ---- common case: one group of 8 slots, 4 per half ----
        int pv = epack[e0 + ((lane < m) ? lane : 0)];
        int p[4];
        #pragma unroll
        for (int k = 0; k < 4; ++k) {
            int i = 2 * k + h2;
            p[k] = (i < m) ? __shfl(pv, i) : ZP;
        }
        uint2 x[4]; uint4 w[4];
        #pragma unroll
        for (int k = 0; k < 4; ++k) x[k] = *(const uint2*)(hbb + (p[k] & 0xFFFFFF00u) + hoff);
        #pragma unroll
        for (int k = 0; k < 4; ++k) w[k] = *(const uint4*)(wbb + ((p[k] & 255) << 9) + woff);
        #pragma unroll
        for (int k = 0; k < 4; ++k) {
            dot2acc(a0, x[k].x, w[k].x); dot2acc(a1, x[k].x, w[k].y);
            dot2acc(a2, x[k].y, w[k].z); dot2acc(a3, x[k].y, w[k].w);
        }
    } else {
        // ---- straggler path: 16 slots per iteration, 8 per half ----
        for (int base = 0; base < m; base += 64) {
            int cnt = m - base;
            if (cnt > 64) cnt = 64;
            int pv = epack[e0 + base + ((lane < cnt) ? lane : 0)];
            for (int j = 0; j < cnt; j += 16) {
                int p[8];
                #pragma unroll
                for (int k = 0; k < 8; ++k) {
                    int i = j + 2 * k + h2;
                    p[k] = (i < cnt) ? __shfl(pv, i) : ZP;
                }
                uint2 x[8]; uint4 w[8];
                #pragma unroll
                for (int k = 0; k < 8; ++k) x[k] = *(const uint2*)(hbb + (p[k] & 0xFFFFFF00u) + hoff);
                #pragma unroll
                for (int k = 0; k < 8; ++k) w[k] = *(const uint4*)(wbb + ((p[k] & 255) << 9) + woff);
                #pragma unroll
                for (int k = 0; k < 8; ++k) {
                    dot2acc(a0, x[k].x, w[k].x); dot2acc(a1, x[k].x, w[k].y);
                    dot2acc(a2, x[k].y, w[k].z); dot2acc(a3, x[k].y, w[k].w);
                }
            }
        }
    }
    a0 += __shfl_xor(a0, 32);
    a1 += __shfl_xor(a1, 32);
    a2 += __shfl_xor(a2, 32);
    a3 += __shfl_xor(a3, 32);
    if (h2 == 0) {
        uint2 pk;
        pk.x = pkbf(a0 * nv, a1 * nv);
        pk.y = pkbf(a2 * nv, a3 * nv);
        *(uint2*)(aggb + (size_t)n * DD + hl * 4) = pk;
    }
}

// ===========================================================================
// Apply: h_next[n,:] = rrelu( agg[n,:] + h[n,:] @ W )  via bf16 MFMA 16x16x32.
// A staged from the bf16 h table (pure 16B copies); W from pre-swizzled Wt.
// agg input is bf16. WRITE_BF16=1: write bf16 h_next in-place into hb
// (row-local => safe). WRITE_BF16=0: write f32 d_out.
// ===========================================================================
template<int WRITE_BF16>
__global__ __launch_bounds__(256, 2) void apply_k(const unsigned short* __restrict__ aggb,
                                                  const unsigned short* __restrict__ hb,
                                                  const short* __restrict__ Wt,
                                                  float* __restrict__ outf,
                                                  unsigned short* __restrict__ outb) {
    __shared__ short Ash[DD * DD];   // 32 KB bf16, [row][k] swizzled
    __shared__ short Wsh[DD * DD];   // 32 KB bf16, [col][k] swizzled

    const int tid = threadIdx.x;
    const long n0 = (long)blockIdx.x * 128;

    // ---- stage W: linear 32 KB copy (already swizzled in global) ----
    {
        const float4* wsrc = (const float4*)Wt;
        float4*       wdst = (float4*)Wsh;
        #pragma unroll
        for (int i = 0; i < 8; ++i) wdst[tid + i * 256] = wsrc[tid + i * 256];
    }
    // ---- stage A: row r = tid>>1, k-half hf = tid&1 (16B-unit copies) ----
    {
        const int r  = tid >> 1;
        const int hf = tid & 1;
        long srow = n0 + r;
        if (srow >= NN) srow = NN - 1;            // clamp (writes guarded)
        const unsigned short* hrow = hb + (size_t)srow * DD + hf * 64;
        short* arow = Ash + r * DD;
        #pragma unroll
        for (int uu = 0; uu < 8; ++uu) {
            int u = hf * 8 + uu;
            short8 v = *(const short8*)(hrow + uu * 8);
            *(short8*)(arow + ((u ^ (r & 7)) << 3)) = v;
        }
    }
    __syncthreads();

    const int wv  = tid >> 6;
    const int wm  = wv >> 1;          // wave row 0..1 (64 rows each)
    const int wn  = wv & 1;           // wave col 0..1 (64 cols each)
    const int l16 = tid & 15;
    const int q   = (tid & 63) >> 4;

    f32x4 acc[4][4];
    #pragma unroll
    for (int mt = 0; mt < 4; ++mt)
        #pragma unroll
        for (int nt = 0; nt < 4; ++nt) acc[mt][nt] = (f32x4){0.f, 0.f, 0.f, 0.f};

    union Frag { uint2 u2[2]; short8 s8; };

    #pragma unroll
    for (int ks = 0; ks < 4; ++ks) {
        const int ua   = ks * 4 + (q >> 1);       // unit of k = 32ks + 4q
        const int off8 = 4 * (q & 1);             // elem offset within unit
        short8 af[4], bf[4];
        #pragma unroll
        for (int mt = 0; mt < 4; ++mt) {
            int r = wm * 64 + mt * 16 + l16;
            const short* base = Ash + r * DD;
            Frag fr;
            fr.u2[0] = *(const uint2*)(base + ((ua       ^ (r & 7)) << 3) + off8);
            fr.u2[1] = *(const uint2*)(base + (((ua + 2) ^ (r & 7)) << 3) + off8);
            af[mt] = fr.s8;
        }
        #pragma unroll
        for (int nt = 0; nt < 4; ++nt) {
            int c = wn * 64 + nt * 16 + l16;
            const short* base = Wsh + c * DD;
            Frag fr;
            fr.u2[0] = *(const uint2*)(base + ((ua       ^ (c & 7)) << 3) + off8);
            fr.u2[1] = *(const uint2*)(base + (((ua + 2) ^ (c & 7)) << 3) + off8);
            bf[nt] = fr.s8;
        }
        #pragma unroll
        for (int mt = 0; mt < 4; ++mt)
            #pragma unroll
            for (int nt = 0; nt < 4; ++nt)
                acc[mt][nt] = __builtin_amdgcn_mfma_f32_16x16x32_bf16(
                                  af[mt], bf[nt], acc[mt][nt], 0, 0, 0);
    }

    // ---- epilogue: rrelu(agg + acc) ----
    #pragma unroll
    for (int mt = 0; mt < 4; ++mt) {
        #pragma unroll
        for (int i = 0; i < 4; ++i) {
            long nrow = n0 + wm * 64 + mt * 16 + 4 * q + i;
            if (nrow < NN) {
                #pragma unroll
                for (int nt = 0; nt < 4; ++nt) {
                    int c = wn * 64 + nt * 16 + l16;
                    float g = __uint_as_float((unsigned)aggb[nrow * DD + c] << 16);
                    float v = g + acc[mt][nt][i];
                    v = (v >= 0.f) ? v : v * SLOPE;
                    if (WRITE_BF16) outb[nrow * DD + c] = (unsigned short)f2bf(v);
                    else            outf[nrow * DD + c] = v;
                }
            }
        }
    }
}

extern "C" void kernel_launch(void* const* d_in, const int* in_sizes, int n_in,
                              void* d_out, int out_size, void* d_ws, size_t ws_size,
                              hipStream_t stream) {
    const float* ent_embeds  = (const float*)d_in[0];
    // d_in[1] = rel_embeds (unused by the layer)
    const float* weight      = (const float*)d_in[2];   // [L, R, 256]
    const float* loop_weight = (const float*)d_in[3];   // [L, 128, 128]
    const float* norm        = (const float*)d_in[4];   // [N, 1]
    const int*   node_id     = (const int*)d_in[5];
    const int*   edge_type   = (const int*)d_in[6];
    const int*   src         = (const int*)d_in[7];
    const int*   dst         = (const int*)d_in[8];
    float*       out         = (float*)d_out;

    // Workspace layout (~54 MB total)
    unsigned short* aggb = (unsigned short*)d_ws;                  // N*D bf16 = 25.6 MB
    unsigned short* hb   = aggb + (size_t)NN * DD;                 // (N+1)*D bf16
    int*   cnt    = (int*)(hb + (size_t)(NN + 1) * DD);            // NN
    int*   off    = cnt + NN;                                      // NN+1
    int*   cursor = off + NN + 1;                                  // NN
    int*   bsum   = cursor + NN;                                   // 512
    int*   epack  = bsum + 512;                                    // NE
    short* wt     = (short*)(epack + NE);                          // 2*DD*DD bf16 = 64 KB
    unsigned* wb  = (unsigned*)(wt + 2 * DD * DD);                 // 2*RR*128 uints = 235 KB

    const int NB_E = (NE + 255) / 256;
    const int NB_N = (NN + 255) / 256;

    // ---- one-time prep ----
    hipMemsetAsync(cnt, 0, (size_t)NN * sizeof(int), stream);
    prep_k  <<<PREP_TOT_B, 256, 0, stream>>>(loop_weight, weight, ent_embeds, node_id,
                                             wt, wb, hb);
    hist_k  <<<NB_E, 256, 0, stream>>>(dst, cnt);
    scan1_k <<<NB_N, 256, 0, stream>>>(cnt, off, bsum);
    scan2_k <<<1,    512, 0, stream>>>(bsum, NB_N);
    scan3_k <<<NB_N, 256, 0, stream>>>(off, bsum, cursor);
    scat_k  <<<NB_E, 256, 0, stream>>>(src, edge_type, dst, cursor, epack);

    const int AGG_BLOCKS = (NN * 64) / 256;    // one wave per node
    const int APL_BLOCKS = (NN + 127) / 128;   // 128 rows per block

    // ---- layer 0: agg from hb(=h0), apply writes h1 bf16 in-place into hb ----
    agg_k     <<<AGG_BLOCKS, 256, 0, stream>>>(hb, off, epack, wb, norm, aggb);
    apply_k<1><<<APL_BLOCKS, 256, 0, stream>>>(aggb, hb, wt, nullptr, hb);

    // ---- layer 1: agg from hb(=h1), apply writes final f32 out ----
    agg_k     <<<AGG_BLOCKS, 256, 0, stream>>>(hb, off, epack, wb + (size_t)RR * 128,
                                               norm, aggb);
    apply_k<0><<<APL_BLOCKS, 256, 0, stream>>>(aggb, hb, wt + (size_t)DD * DD, out, nullptr);
}

// Round 10
// 198.812 us; speedup vs baseline: 5.6117x; 1.0216x over previous
//
#include <hip/hip_runtime.h>
#include <hip/hip_bf16.h>

// Problem constants (match reference)
#define NN 100000      // nodes
#define NE 500000      // edges
#define DD 128         // h_dim
#define RR 230         // relation types
// F.rrelu eval-mode slope = (1/8 + 1/3)/2
#define SLOPE 0.2291666666666666667f

// Padded CSR: each node's slot count rounded up to a multiple of 8.
#define EPMAX (NE + 7 * NN)          // 1,200,000 worst-case padded slots
#define ZP (NN << 8)                 // pad slot: points at all-zero hb row NN, type 0

typedef __attribute__((ext_vector_type(8))) short short8;
typedef __attribute__((ext_vector_type(4))) float f32x4;

__device__ __forceinline__ short f2bf(float f) {   // RNE f32 -> bf16 bits
    unsigned u = __float_as_uint(f);
    u += 0x7fffu + ((u >> 16) & 1u);
    return (short)(u >> 16);
}
__device__ __forceinline__ unsigned pkbf(float lo, float hi) {
    return (unsigned)(unsigned short)f2bf(lo) | ((unsigned)(unsigned short)f2bf(hi) << 16);
}

// dot2: acc += x.lo*w.lo + x.hi*w.hi   (bf16 pairs packed in uint)
#if defined(__has_builtin)
#if __has_builtin(__builtin_amdgcn_fdot2_f32_bf16)
#define HAS_DOT2 1
#endif
#endif
__device__ __forceinline__ void dot2acc(float& acc, unsigned x, unsigned w) {
#ifdef HAS_DOT2
    typedef __attribute__((ext_vector_type(2))) __bf16 bf16x2;
    acc = __builtin_amdgcn_fdot2_f32_bf16(__builtin_bit_cast(bf16x2, x),
                                          __builtin_bit_cast(bf16x2, w), acc, false);
#else
    acc = fmaf(__uint_as_float(x << 16),        __uint_as_float(w << 16),
          fmaf(__uint_as_float(x & 0xFFFF0000u), __uint_as_float(w & 0xFFFF0000u), acc));
#endif
}

// ===========================================================================
// p1_k: fused one-time prep, partitioned by blockIdx (all parts independent;
// only dependency is memset(cnt)=0 which precedes this kernel):
//   [0,16)            : loop_weight f32 -> Wt bf16 transposed+swizzled
//   [16,74)           : relation weights -> packed bf16 pair table wb
//   [74,1246)         : epack prefilled with ZP (pad slots read zero row)
//   [1246,7497)       : hb[n] = bf16(ent[node_id[n]]); row NN = zeros
//   [7497,9451)       : hist: cnt[dst[e]]++
// ===========================================================================
#define P1_WT_E   16
#define P1_WB_E   74
#define P1_FL_E   (74 + (EPMAX / 4 + 255) / 256)                 // 74+1172 = 1246
#define P1_HB_E   (P1_FL_E + ((NN + 1) * 16 + 255) / 256)        // +6251   = 7497
#define P1_TOT    (P1_HB_E + (NE + 255) / 256)                   // +1954   = 9451

__global__ __launch_bounds__(256) void p1_k(const float* __restrict__ lw,
                                            const float* __restrict__ weight,
                                            const float* __restrict__ ent,
                                            const int* __restrict__ nid,
                                            const int* __restrict__ dst,
                                            short* __restrict__ wt,
                                            unsigned* __restrict__ wb,
                                            unsigned short* __restrict__ hb,
                                            int* __restrict__ epack,
                                            int* __restrict__ cnt) {
    int bid = blockIdx.x;
    if (bid < P1_WT_E) {
        // ---- Wt[l][c][k] bf16, 16B-unit swizzle u^(c&7) ----
        int gid = bid * 256 + threadIdx.x;
        if (gid >= 2 * DD * 16) return;
        int l   = gid >> 11;
        int rem = gid & 2047;
        int c   = rem >> 4;
        int u   = rem & 15;
        const float* wsrc = lw + l * DD * DD + c;   // stride DD over k
        short8 v;
        #pragma unroll
        for (int j = 0; j < 8; ++j) v[j] = f2bf(wsrc[(u * 8 + j) * DD]);
        *(short8*)(wt + (size_t)l * DD * DD + c * DD + ((u ^ (c & 7)) << 3)) = v;
    } else if (bid < P1_WB_E) {
        // ---- packed bf16 pairs per (l,t,hl) ----
        int gid = (bid - P1_WT_E) * 256 + threadIdx.x;
        if (gid >= 2 * RR * 32) return;
        int lt = gid >> 5;           // l*RR + t
        int hl = gid & 31;
        const float* wsrc = weight + (size_t)lt * 256 + hl * 8;   // blocks 2hl, 2hl+1
        float4 f0 = *(const float4*)wsrc;        // b0: (i0o0,i0o1,i1o0,i1o1)
        float4 f1 = *(const float4*)(wsrc + 4);  // b1
        uint4 v;
        v.x = pkbf(f0.x, f0.z);   // b0, o=0
        v.y = pkbf(f0.y, f0.w);   // b0, o=1
        v.z = pkbf(f1.x, f1.z);   // b1, o=0
        v.w = pkbf(f1.y, f1.w);   // b1, o=1
        *(uint4*)(wb + (size_t)lt * 128 + hl * 4) = v;
    } else if (bid < P1_FL_E) {
        // ---- epack prefill with ZP (uint4 stores) ----
        int idx = (bid - P1_WB_E) * 256 + threadIdx.x;   // uint4 index
        if (idx * 4 >= EPMAX) return;
        int4 z = make_int4(ZP, ZP, ZP, ZP);
        *(int4*)(epack + idx * 4) = z;
    } else if (bid < P1_HB_E) {
        // ---- hb[n] = bf16(ent[nid[n]]); row NN = zeros ----
        int gid = (bid - P1_FL_E) * 256 + threadIdx.x;
        if (gid >= (NN + 1) * 16) return;
        int n = gid >> 4;
        int u = gid & 15;
        short8 v = {0, 0, 0, 0, 0, 0, 0, 0};
        if (n < NN) {
            const float* srcp = ent + (size_t)nid[n] * DD + u * 8;
            float4 f0 = *(const float4*)srcp;
            float4 f1 = *(const float4*)(srcp + 4);
            v[0] = f2bf(f0.x); v[1] = f2bf(f0.y); v[2] = f2bf(f0.z); v[3] = f2bf(f0.w);
            v[4] = f2bf(f1.x); v[5] = f2bf(f1.y); v[6] = f2bf(f1.z); v[7] = f2bf(f1.w);
        }
        *(short8*)(hb + (size_t)n * DD + u * 8) = v;
    } else {
        // ---- hist: cnt[dst[e]]++ ----
        int e = (bid - P1_HB_E) * 256 + threadIdx.x;
        if (e >= NE) return;
        atomicAdd(&cnt[dst[e]], 1);
    }
}

// ===========================================================================
// scan1: block-local exclusive scan of PADDED counts ((cnt+7)&~7)
// ===========================================================================
__global__ __launch_bounds__(256) void scan1_k(const int* __restrict__ cnt,
                                               int* __restrict__ off,
                                               int* __restrict__ bsum) {
    __shared__ int sh[256];
    int i = blockIdx.x * 256 + threadIdx.x;
    int v = (i < NN) ? ((cnt[i] + 7) & ~7) : 0;
    sh[threadIdx.x] = v;
    __syncthreads();
    for (int d = 1; d < 256; d <<= 1) {
        int t = (threadIdx.x >= d) ? sh[threadIdx.x - d] : 0;
        __syncthreads();
        sh[threadIdx.x] += t;
        __syncthreads();
    }
    if (i < NN) off[i] = sh[threadIdx.x] - v;          // exclusive (local)
    if (threadIdx.x == 255) bsum[blockIdx.x] = sh[255];
}

// ===========================================================================
// scan23: each block re-derives its bsum prefix (256-thread reduce over
// bsum[0..bid)), adds to local offsets, seeds cursor; last block writes
// off[NN] = grand total. Replaces scan2+scan3.
// ===========================================================================
__global__ __launch_bounds__(256) void scan23_k(int* __restrict__ off,
                                                const int* __restrict__ bsum,
                                                int* __restrict__ cursor,
                                                int nb) {
    __shared__ int sh[256];
    const int bid = blockIdx.x;
    const int tid = threadIdx.x;
    int s = 0;
    if (tid < bid) s = bsum[tid];
    if (tid + 256 < bid) s += bsum[tid + 256];
    sh[tid] = s;
    __syncthreads();
    #pragma unroll
    for (int d = 128; d > 0; d >>= 1) {
        if (tid < d) sh[tid] += sh[tid + d];
        __syncthreads();
    }
    const int S = sh[0];
    int i = bid * 256 + tid;
    if (i < NN) {
        int o = off[i] + S;
        off[i] = o;
        cursor[i] = o;
    }
    if (bid == nb - 1 && tid == 0) off[NN] = S + bsum[bid];
}

__global__ __launch_bounds__(256) void scat_k(const int* __restrict__ src,
                                              const int* __restrict__ et,
                                              const int* __restrict__ dst,
                                              int* __restrict__ cursor,
                                              int* __restrict__ epack) {
    int e = blockIdx.x * 256 + threadIdx.x;
    if (e >= NE) return;
    int pos = atomicAdd(&cursor[dst[e]], 1);
    epack[pos] = (src[e] << 8) | et[e];
}

// ===========================================================================
// Aggregate: one wave per dst node, PADDED slots -> branch-free, mask-free.
// 32 lanes per edge (lane covers 4 dims = 2 basis blocks); halves process
// interleaved slots. Pad slots read the all-zero hb row (contribute 0).
// Row byte-offset = p & ~255 (pack trick).
// ===========================================================================
__global__ __launch_bounds__(256) void agg_k(const unsigned short* __restrict__ hb,
                                             const int* __restrict__ off,
                                             const int* __restrict__ epack,
                                             const unsigned* __restrict__ wb,  // packed pairs, this layer
                                             const float* __restrict__ norm,
                                             unsigned short* __restrict__ aggb) {
    int n    = (blockIdx.x * 256 + threadIdx.x) >> 6;
    int lane = threadIdx.x & 63;
    int hl   = lane & 31;        // dim group: dims 4hl..4hl+3 (blocks 2hl, 2hl+1)
    int h2   = lane >> 5;        // half: handles slots 2k+h2 of each group
    if (n >= NN) return;
    int e0 = off[n];
    int m  = off[n + 1] - e0;    // multiple of 8 (padded)
    float nv = norm[n];
    float a0 = 0.f, a1 = 0.f, a2 = 0.f, a3 = 0.f;
    const char* hbb = (const char*)hb + hl * 8;   // + dim offset within row
    const char* wbb = (const char*)wb + hl * 16;  // + offset within packed w row

    for (int j = 0; j < m; j += 8) {
        int pv = epack[e0 + j + (lane & 7)];      // group-local 8 slots
        int p0 = __shfl(pv, h2);
        int p1 = __shfl(pv, 2 + h2);
        int p2 = __shfl(pv, 4 + h2);
        int p3 = __shfl(pv, 6 + h2);
        uint2 x0 = *(const uint2*)(hbb + (p0 & 0xFFFFFF00u));
        uint2 x1 = *(const uint2*)(hbb + (p1 & 0xFFFFFF00u));
        uint2 x2 = *(const uint2*)(hbb + (p2 & 0xFFFFFF00u));
        uint2 x3 = *(const uint2*)(hbb + (p3 & 0xFFFFFF00u));
        uint4 w0 = *(const uint4*)(wbb + ((p0 & 255) << 9));
        uint4 w1 = *(const uint4*)(wbb + ((p1 & 255) << 9));
        uint4 w2 = *(const uint4*)(wbb + ((p2 & 255) << 9));
        uint4 w3 = *(const uint4*)(wbb + ((p3 & 255) << 9));
        dot2acc(a0, x0.x, w0.x); dot2acc(a1, x0.x, w0.y);
        dot2acc(a2, x0.y, w0.z); dot2acc(a3, x0.y, w0.w);
        dot2acc(a0, x1.x, w1.x); dot2acc(a1, x1.x, w1.y);
        dot2acc(a2, x1.y, w1.z); dot2acc(a3, x1.y, w1.w);
        dot2acc(a0, x2.x, w2.x); dot2acc(a1, x2.x, w2.y);
        dot2acc(a2, x2.y, w2.z); dot2acc(a3, x2.y, w2.w);
        dot2acc(a0, x3.x, w3.x); dot2acc(a1, x3.x, w3.y);
        dot2acc(a2, x3.y, w3.z); dot2acc(a3, x3.y, w3.w);
    }
    a0 += __shfl_xor(a0, 32);
    a1 += __shfl_xor(a1, 32);
    a2 += __shfl_xor(a2, 32);
    a3 += __shfl_xor(a3, 32);
    if (h2 == 0) {
        uint2 pk;
        pk.x = pkbf(a0 * nv, a1 * nv);
        pk.y = pkbf(a2 * nv, a3 * nv);
        *(uint2*)(aggb + (size_t)n * DD + hl * 4) = pk;
    }
}

// ===========================================================================
// Apply: h_next[n,:] = rrelu( agg[n,:] + h[n,:] @ W )  via bf16 MFMA 16x16x32.
// A staged from the bf16 h table (pure 16B copies); W from pre-swizzled Wt.
// agg input is bf16. WRITE_BF16=1: write bf16 h_next in-place into hb
// (row-local => safe). WRITE_BF16=0: write f32 d_out.
// ===========================================================================
template<int WRITE_BF16>
__global__ __launch_bounds__(256, 2) void apply_k(const unsigned short* __restrict__ aggb,
                                                  const unsigned short* __restrict__ hb,
                                                  const short* __restrict__ Wt,
                                                  float* __restrict__ outf,
                                                  unsigned short* __restrict__ outb) {
    __shared__ short Ash[DD * DD];   // 32 KB bf16, [row][k] swizzled
    __shared__ short Wsh[DD * DD];   // 32 KB bf16, [col][k] swizzled

    const int tid = threadIdx.x;
    const long n0 = (long)blockIdx.x * 128;

    // ---- stage W: linear 32 KB copy (already swizzled in global) ----
    {
        const float4* wsrc = (const float4*)Wt;
        float4*       wdst = (float4*)Wsh;
        #pragma unroll
        for (int i = 0; i < 8; ++i) wdst[tid + i * 256] = wsrc[tid + i * 256];
    }
    // ---- stage A: row r = tid>>1, k-half hf = tid&1 (16B-unit copies) ----
    {
        const int r  = tid >> 1;
        const int hf = tid & 1;
        long srow = n0 + r;
        if (srow >= NN) srow = NN - 1;            // clamp (writes guarded)
        const unsigned short* hrow = hb + (size_t)srow * DD + hf * 64;
        short* arow = Ash + r * DD;
        #pragma unroll
        for (int uu = 0; uu < 8; ++uu) {
            int u = hf * 8 + uu;
            short8 v = *(const short8*)(hrow + uu * 8);
            *(short8*)(arow + ((u ^ (r & 7)) << 3)) = v;
        }
    }
    __syncthreads();

    const int wv  = tid >> 6;
    const int wm  = wv >> 1;          // wave row 0..1 (64 rows each)
    const int wn  = wv & 1;           // wave col 0..1 (64 cols each)
    const int l16 = tid & 15;
    const int q   = (tid & 63) >> 4;

    f32x4 acc[4][4];
    #pragma unroll
    for (int mt = 0; mt < 4; ++mt)
        #pragma unroll
        for (int nt = 0; nt < 4; ++nt) acc[mt][nt] = (f32x4){0.f, 0.f, 0.f, 0.f};

    union Frag { uint2 u2[2]; short8 s8; };

    #pragma unroll
    for (int ks = 0; ks < 4; ++ks) {
        const int ua   = ks * 4 + (q >> 1);       // unit of k = 32ks + 4q
        const int off8 = 4 * (q & 1);             // elem offset within unit
        short8 af[4], bf[4];
        #pragma unroll
        for (int mt = 0; mt < 4; ++mt) {
            int r = wm * 64 + mt * 16 + l16;
            const short* base = Ash + r * DD;
            Frag fr;
            fr.u2[0] = *(const uint2*)(base + ((ua       ^ (r & 7)) << 3) + off8);
            fr.u2[1] = *(const uint2*)(base + (((ua + 2) ^ (r & 7)) << 3) + off8);
            af[mt] = fr.s8;
        }
        #pragma unroll
        for (int nt = 0; nt < 4; ++nt) {
            int c = wn * 64 + nt * 16 + l16;
            const short* base = Wsh + c * DD;
            Frag fr;
            fr.u2[0] = *(const uint2*)(base + ((ua       ^ (c & 7)) << 3) + off8);
            fr.u2[1] = *(const uint2*)(base + (((ua + 2) ^ (c & 7)) << 3) + off8);
            bf[nt] = fr.s8;
        }
        #pragma unroll
        for (int mt = 0; mt < 4; ++mt)
            #pragma unroll
            for (int nt = 0; nt < 4; ++nt)
                acc[mt][nt] = __builtin_amdgcn_mfma_f32_16x16x32_bf16(
                                  af[mt], bf[nt], acc[mt][nt], 0, 0, 0);
    }

    // ---- epilogue: rrelu(agg + acc) ----
    #pragma unroll
    for (int mt = 0; mt < 4; ++mt) {
        #pragma unroll
        for (int i = 0; i < 4; ++i) {
            long nrow = n0 + wm * 64 + mt * 16 + 4 * q + i;
            if (nrow < NN) {
                #pragma unroll
                for (int nt = 0; nt < 4; ++nt) {
                    int c = wn * 64 + nt * 16 + l16;
                    float g = __uint_as_float((unsigned)aggb[nrow * DD + c] << 16);
                    float v = g + acc[mt][nt][i];
                    v = (v >= 0.f) ? v : v * SLOPE;
                    if (WRITE_BF16) outb[nrow * DD + c] = (unsigned short)f2bf(v);
                    else            outf[nrow * DD + c] = v;
                }
            }
        }
    }
}

extern "C" void kernel_launch(void* const* d_in, const int* in_sizes, int n_in,
                              void* d_out, int out_size, void* d_ws, size_t ws_size,
                              hipStream_t stream) {
    const float* ent_embeds  = (const float*)d_in[0];
    // d_in[1] = rel_embeds (unused by the layer)
    const float* weight      = (const float*)d_in[2];   // [L, R, 256]
    const float* loop_weight = (const float*)d_in[3];   // [L, 128, 128]
    const float* norm        = (const float*)d_in[4];   // [N, 1]
    const int*   node_id     = (const int*)d_in[5];
    const int*   edge_type   = (const int*)d_in[6];
    const int*   src         = (const int*)d_in[7];
    const int*   dst         = (const int*)d_in[8];
    float*       out         = (float*)d_out;

    // Workspace layout (~58 MB total)
    unsigned short* aggb = (unsigned short*)d_ws;                  // N*D bf16 = 25.6 MB
    unsigned short* hb   = aggb + (size_t)NN * DD;                 // (N+1)*D bf16
    int*   cnt    = (int*)(hb + (size_t)(NN + 1) * DD);            // NN
    int*   off    = cnt + NN;                                      // NN+1
    int*   cursor = off + NN + 1;                                  // NN
    int*   epack  = cursor + NN;                                   // EPMAX (padded)
    int*   bsum   = epack + EPMAX;                                 // 512
    short* wt     = (short*)(bsum + 512);                          // 2*DD*DD bf16 = 64 KB
    unsigned* wb  = (unsigned*)(wt + 2 * DD * DD);                 // 2*RR*128 uints = 235 KB

    const int NB_E = (NE + 255) / 256;
    const int NB_N = (NN + 255) / 256;

    // ---- one-time prep: memset -> fused prep/fill/hist -> scans -> scatter ----
    hipMemsetAsync(cnt, 0, (size_t)NN * sizeof(int), stream);
    p1_k    <<<P1_TOT, 256, 0, stream>>>(loop_weight, weight, ent_embeds, node_id, dst,
                                         wt, wb, hb, epack, cnt);
    scan1_k <<<NB_N, 256, 0, stream>>>(cnt, off, bsum);
    scan23_k<<<NB_N, 256, 0, stream>>>(off, bsum, cursor, NB_N);
    scat_k  <<<NB_E, 256, 0, stream>>>(src, edge_type, dst, cursor, epack);

    const int AGG_BLOCKS = (NN * 64) / 256;    // one wave per node
    const int APL_BLOCKS = (NN + 127) / 128;   // 128 rows per block

    // ---- layer 0: agg from hb(=h0), apply writes h1 bf16 in-place into hb ----
    agg_k     <<<AGG_BLOCKS, 256, 0, stream>>>(hb, off, epack, wb, norm, aggb);
    apply_k<1><<<APL_BLOCKS, 256, 0, stream>>>(aggb, hb, wt, nullptr, hb);

    // ---- layer 1: agg from hb(=h1), apply writes final f32 out ----
    agg_k     <<<AGG_BLOCKS, 256, 0, stream>>>(hb, off, epack, wb + (size_t)RR * 128,
                                               norm, aggb);
    apply_k<0><<<APL_BLOCKS, 256, 0, stream>>>(aggb, hb, wt + (size_t)DD * DD, out, nullptr);
}

// Round 11
// 197.468 us; speedup vs baseline: 5.6499x; 1.0068x over previous
//
#include <hip/hip_runtime.h>
#include <hip/hip_bf16.h>

// Problem constants (match reference)
#define NN 100000      // nodes
#define NE 500000      // edges
#define DD 128         // h_dim
#define RR 230         // relation types
// F.rrelu eval-mode slope = (1/8 + 1/3)/2
#define SLOPE 0.2291666666666666667f

// Padded CSR: each node's slot count rounded up to a multiple of 8.
#define EPMAX (NE + 7 * NN)          // 1,200,000 worst-case padded slots
#define ZP (NN << 8)                 // pad slot: points at all-zero hb row NN, type 0

typedef __attribute__((ext_vector_type(8))) short short8;
typedef __attribute__((ext_vector_type(4))) float f32x4;

__device__ __forceinline__ short f2bf(float f) {   // RNE f32 -> bf16 bits
    unsigned u = __float_as_uint(f);
    u += 0x7fffu + ((u >> 16) & 1u);
    return (short)(u >> 16);
}
__device__ __forceinline__ unsigned pkbf(float lo, float hi) {
    return (unsigned)(unsigned short)f2bf(lo) | ((unsigned)(unsigned short)f2bf(hi) << 16);
}

// dot2: acc += x.lo*w.lo + x.hi*w.hi   (bf16 pairs packed in uint)
#if defined(__has_builtin)
#if __has_builtin(__builtin_amdgcn_fdot2_f32_bf16)
#define HAS_DOT2 1
#endif
#endif
__device__ __forceinline__ void dot2acc(float& acc, unsigned x, unsigned w) {
#ifdef HAS_DOT2
    typedef __attribute__((ext_vector_type(2))) __bf16 bf16x2;
    acc = __builtin_amdgcn_fdot2_f32_bf16(__builtin_bit_cast(bf16x2, x),
                                          __builtin_bit_cast(bf16x2, w), acc, false);
#else
    acc = fmaf(__uint_as_float(x << 16),        __uint_as_float(w << 16),
          fmaf(__uint_as_float(x & 0xFFFF0000u), __uint_as_float(w & 0xFFFF0000u), acc));
#endif
}

// ===========================================================================
// zero_k: cnt = 0 (replaces hipMemsetAsync's 42 us runtime fill kernel)
// ===========================================================================
__global__ __launch_bounds__(256) void zero_k(int* __restrict__ cnt) {
    int i = blockIdx.x * 256 + threadIdx.x;          // int4 index
    if (i * 4 < NN) *(int4*)(cnt + i * 4) = make_int4(0, 0, 0, 0);
}

// ===========================================================================
// p1_k: fused one-time prep, partitioned by blockIdx (all parts independent;
// only dependency is zero_k(cnt) which precedes this kernel):
//   [0,16)        : loop_weight f32 -> Wt bf16 transposed+swizzled
//   [16,74)       : relation weights -> packed bf16 pair table wb
//   [74,P1_FL_E)  : epack prefilled with ZP (pad slots read zero row)
//   [..,P1_HB_E)  : hb[n] = bf16(ent[node_id[n]]); row NN = zeros
//   [..,P1_TOT)   : hist: cnt[dst[e]]++
// ===========================================================================
#define P1_WT_E   16
#define P1_WB_E   74
#define P1_FL_E   (74 + (EPMAX / 4 + 255) / 256)                 // 74+1172 = 1246
#define P1_HB_E   (P1_FL_E + ((NN + 1) * 16 + 255) / 256)        // +6251   = 7497
#define P1_TOT    (P1_HB_E + (NE + 255) / 256)                   // +1954   = 9451

__global__ __launch_bounds__(256) void p1_k(const float* __restrict__ lw,
                                            const float* __restrict__ weight,
                                            const float* __restrict__ ent,
                                            const int* __restrict__ nid,
                                            const int* __restrict__ dst,
                                            short* __restrict__ wt,
                                            unsigned* __restrict__ wb,
                                            unsigned short* __restrict__ hb,
                                            int* __restrict__ epack,
                                            int* __restrict__ cnt) {
    int bid = blockIdx.x;
    if (bid < P1_WT_E) {
        // ---- Wt[l][c][k] bf16, 16B-unit swizzle u^(c&7) ----
        int gid = bid * 256 + threadIdx.x;
        if (gid >= 2 * DD * 16) return;
        int l   = gid >> 11;
        int rem = gid & 2047;
        int c   = rem >> 4;
        int u   = rem & 15;
        const float* wsrc = lw + l * DD * DD + c;   // stride DD over k
        short8 v;
        #pragma unroll
        for (int j = 0; j < 8; ++j) v[j] = f2bf(wsrc[(u * 8 + j) * DD]);
        *(short8*)(wt + (size_t)l * DD * DD + c * DD + ((u ^ (c & 7)) << 3)) = v;
    } else if (bid < P1_WB_E) {
        // ---- packed bf16 pairs per (l,t,hl) ----
        int gid = (bid - P1_WT_E) * 256 + threadIdx.x;
        if (gid >= 2 * RR * 32) return;
        int lt = gid >> 5;           // l*RR + t
        int hl = gid & 31;
        const float* wsrc = weight + (size_t)lt * 256 + hl * 8;   // blocks 2hl, 2hl+1
        float4 f0 = *(const float4*)wsrc;        // b0: (i0o0,i0o1,i1o0,i1o1)
        float4 f1 = *(const float4*)(wsrc + 4);  // b1
        uint4 v;
        v.x = pkbf(f0.x, f0.z);   // b0, o=0
        v.y = pkbf(f0.y, f0.w);   // b0, o=1
        v.z = pkbf(f1.x, f1.z);   // b1, o=0
        v.w = pkbf(f1.y, f1.w);   // b1, o=1
        *(uint4*)(wb + (size_t)lt * 128 + hl * 4) = v;
    } else if (bid < P1_FL_E) {
        // ---- epack prefill with ZP (uint4 stores) ----
        int idx = (bid - P1_WB_E) * 256 + threadIdx.x;   // uint4 index
        if (idx * 4 >= EPMAX) return;
        *(int4*)(epack + idx * 4) = make_int4(ZP, ZP, ZP, ZP);
    } else if (bid < P1_HB_E) {
        // ---- hb[n] = bf16(ent[nid[n]]); row NN = zeros ----
        int gid = (bid - P1_FL_E) * 256 + threadIdx.x;
        if (gid >= (NN + 1) * 16) return;
        int n = gid >> 4;
        int u = gid & 15;
        short8 v = {0, 0, 0, 0, 0, 0, 0, 0};
        if (n < NN) {
            const float* srcp = ent + (size_t)nid[n] * DD + u * 8;
            float4 f0 = *(const float4*)srcp;
            float4 f1 = *(const float4*)(srcp + 4);
            v[0] = f2bf(f0.x); v[1] = f2bf(f0.y); v[2] = f2bf(f0.z); v[3] = f2bf(f0.w);
            v[4] = f2bf(f1.x); v[5] = f2bf(f1.y); v[6] = f2bf(f1.z); v[7] = f2bf(f1.w);
        }
        *(short8*)(hb + (size_t)n * DD + u * 8) = v;
    } else {
        // ---- hist: cnt[dst[e]]++ ----
        int e = (bid - P1_HB_E) * 256 + threadIdx.x;
        if (e >= NE) return;
        atomicAdd(&cnt[dst[e]], 1);
    }
}

// ===========================================================================
// scan1: block-local exclusive scan of PADDED counts ((cnt+7)&~7)
// ===========================================================================
__global__ __launch_bounds__(256) void scan1_k(const int* __restrict__ cnt,
                                               int* __restrict__ off,
                                               int* __restrict__ bsum) {
    __shared__ int sh[256];
    int i = blockIdx.x * 256 + threadIdx.x;
    int v = (i < NN) ? ((cnt[i] + 7) & ~7) : 0;
    sh[threadIdx.x] = v;
    __syncthreads();
    for (int d = 1; d < 256; d <<= 1) {
        int t = (threadIdx.x >= d) ? sh[threadIdx.x - d] : 0;
        __syncthreads();
        sh[threadIdx.x] += t;
        __syncthreads();
    }
    if (i < NN) off[i] = sh[threadIdx.x] - v;          // exclusive (local)
    if (threadIdx.x == 255) bsum[blockIdx.x] = sh[255];
}

// ===========================================================================
// scan23: each block re-derives its bsum prefix (256-thread reduce), adds to
// local offsets, seeds cursor; last block writes off[NN] = grand total.
// ===========================================================================
__global__ __launch_bounds__(256) void scan23_k(int* __restrict__ off,
                                                const int* __restrict__ bsum,
                                                int* __restrict__ cursor,
                                                int nb) {
    __shared__ int sh[256];
    const int bid = blockIdx.x;
    const int tid = threadIdx.x;
    int s = 0;
    if (tid < bid) s = bsum[tid];
    if (tid + 256 < bid) s += bsum[tid + 256];
    sh[tid] = s;
    __syncthreads();
    #pragma unroll
    for (int d = 128; d > 0; d >>= 1) {
        if (tid < d) sh[tid] += sh[tid + d];
        __syncthreads();
    }
    const int S = sh[0];
    int i = bid * 256 + tid;
    if (i < NN) {
        int o = off[i] + S;
        off[i] = o;
        cursor[i] = o;
    }
    if (bid == nb - 1 && tid == 0) off[NN] = S + bsum[bid];
}

__global__ __launch_bounds__(256) void scat_k(const int* __restrict__ src,
                                              const int* __restrict__ et,
                                              const int* __restrict__ dst,
                                              int* __restrict__ cursor,
                                              int* __restrict__ epack) {
    int e = blockIdx.x * 256 + threadIdx.x;
    if (e >= NE) return;
    int pos = atomicAdd(&cursor[dst[e]], 1);
    epack[pos] = (src[e] << 8) | et[e];
}

// ===========================================================================
// Aggregate: one wave per dst node, PADDED slots, branch/mask/shfl-free.
// Half h2 owns slot quad {4*h2..4*h2+3} of each 8-slot group (slot placement
// within a group is arbitrary -> positional split is valid) and reads its 4
// edge-pointers with ONE broadcast uint4 load. Pad slots hit the zero row.
// ===========================================================================
__global__ __launch_bounds__(256) void agg_k(const unsigned short* __restrict__ hb,
                                             const int* __restrict__ off,
                                             const int* __restrict__ epack,
                                             const unsigned* __restrict__ wb,  // packed pairs, this layer
                                             const float* __restrict__ norm,
                                             unsigned short* __restrict__ aggb) {
    int n    = (blockIdx.x * 256 + threadIdx.x) >> 6;
    int lane = threadIdx.x & 63;
    int hl   = lane & 31;        // dim group: dims 4hl..4hl+3 (blocks 2hl, 2hl+1)
    int h2   = lane >> 5;        // half: owns slot quad 4*h2..4*h2+3
    if (n >= NN) return;
    int e0 = off[n];
    int m  = off[n + 1] - e0;    // multiple of 8 (padded)
    float nv = norm[n];
    float a0 = 0.f, a1 = 0.f, a2 = 0.f, a3 = 0.f;
    const char* hbb = (const char*)hb + hl * 8;   // + dim offset within row
    const char* wbb = (const char*)wb + hl * 16;  // + offset within packed w row
    const int*  ep  = epack + e0 + h2 * 4;

    for (int j = 0; j < m; j += 8) {
        uint4 pv = *(const uint4*)(ep + j);       // broadcast 16B: 4 slot pointers
        uint2 x0 = *(const uint2*)(hbb + (pv.x & 0xFFFFFF00u));
        uint2 x1 = *(const uint2*)(hbb + (pv.y & 0xFFFFFF00u));
        uint2 x2 = *(const uint2*)(hbb + (pv.z & 0xFFFFFF00u));
        uint2 x3 = *(const uint2*)(hbb + (pv.w & 0xFFFFFF00u));
        uint4 w0 = *(const uint4*)(wbb + ((pv.x & 255) << 9));
        uint4 w1 = *(const uint4*)(wbb + ((pv.y & 255) << 9));
        uint4 w2 = *(const uint4*)(wbb + ((pv.z & 255) << 9));
        uint4 w3 = *(const uint4*)(wbb + ((pv.w & 255) << 9));
        dot2acc(a0, x0.x, w0.x); dot2acc(a1, x0.x, w0.y);
        dot2acc(a2, x0.y, w0.z); dot2acc(a3, x0.y, w0.w);
        dot2acc(a0, x1.x, w1.x); dot2acc(a1, x1.x, w1.y);
        dot2acc(a2, x1.y, w1.z); dot2acc(a3, x1.y, w1.w);
        dot2acc(a0, x2.x, w2.x); dot2acc(a1, x2.x, w2.y);
        dot2acc(a2, x2.y, w2.z); dot2acc(a3, x2.y, w2.w);
        dot2acc(a0, x3.x, w3.x); dot2acc(a1, x3.x, w3.y);
        dot2acc(a2, x3.y, w3.z); dot2acc(a3, x3.y, w3.w);
    }
    a0 += __shfl_xor(a0, 32);
    a1 += __shfl_xor(a1, 32);
    a2 += __shfl_xor(a2, 32);
    a3 += __shfl_xor(a3, 32);
    if (h2 == 0) {
        uint2 pk;
        pk.x = pkbf(a0 * nv, a1 * nv);
        pk.y = pkbf(a2 * nv, a3 * nv);
        *(uint2*)(aggb + (size_t)n * DD + hl * 4) = pk;
    }
}

// ===========================================================================
// Apply: h_next[n,:] = rrelu( agg[n,:] + h[n,:] @ W )  via bf16 MFMA 16x16x32.
// A staged from the bf16 h table (pure 16B copies); W from pre-swizzled Wt.
// agg input is bf16. WRITE_BF16=1: write bf16 h_next in-place into hb
// (row-local => safe). WRITE_BF16=0: write f32 d_out.
// ===========================================================================
template<int WRITE_BF16>
__global__ __launch_bounds__(256, 2) void apply_k(const unsigned short* __restrict__ aggb,
                                                  const unsigned short* __restrict__ hb,
                                                  const short* __restrict__ Wt,
                                                  float* __restrict__ outf,
                                                  unsigned short* __restrict__ outb) {
    __shared__ short Ash[DD * DD];   // 32 KB bf16, [row][k] swizzled
    __shared__ short Wsh[DD * DD];   // 32 KB bf16, [col][k] swizzled

    const int tid = threadIdx.x;
    const long n0 = (long)blockIdx.x * 128;

    // ---- stage W: linear 32 KB copy (already swizzled in global) ----
    {
        const float4* wsrc = (const float4*)Wt;
        float4*       wdst = (float4*)Wsh;
        #pragma unroll
        for (int i = 0; i < 8; ++i) wdst[tid + i * 256] = wsrc[tid + i * 256];
    }
    // ---- stage A: row r = tid>>1, k-half hf = tid&1 (16B-unit copies) ----
    {
        const int r  = tid >> 1;
        const int hf = tid & 1;
        long srow = n0 + r;
        if (srow >= NN) srow = NN - 1;            // clamp (writes guarded)
        const unsigned short* hrow = hb + (size_t)srow * DD + hf * 64;
        short* arow = Ash + r * DD;
        #pragma unroll
        for (int uu = 0; uu < 8; ++uu) {
            int u = hf * 8 + uu;
            short8 v = *(const short8*)(hrow + uu * 8);
            *(short8*)(arow + ((u ^ (r & 7)) << 3)) = v;
        }
    }
    __syncthreads();

    const int wv  = tid >> 6;
    const int wm  = wv >> 1;          // wave row 0..1 (64 rows each)
    const int wn  = wv & 1;           // wave col 0..1 (64 cols each)
    const int l16 = tid & 15;
    const int q   = (tid & 63) >> 4;

    f32x4 acc[4][4];
    #pragma unroll
    for (int mt = 0; mt < 4; ++mt)
        #pragma unroll
        for (int nt = 0; nt < 4; ++nt) acc[mt][nt] = (f32x4){0.f, 0.f, 0.f, 0.f};

    union Frag { uint2 u2[2]; short8 s8; };

    #pragma unroll
    for (int ks = 0; ks < 4; ++ks) {
        const int ua   = ks * 4 + (q >> 1);       // unit of k = 32ks + 4q
        const int off8 = 4 * (q & 1);             // elem offset within unit
        short8 af[4], bf[4];
        #pragma unroll
        for (int mt = 0; mt < 4; ++mt) {
            int r = wm * 64 + mt * 16 + l16;
            const short* base = Ash + r * DD;
            Frag fr;
            fr.u2[0] = *(const uint2*)(base + ((ua       ^ (r & 7)) << 3) + off8);
            fr.u2[1] = *(const uint2*)(base + (((ua + 2) ^ (r & 7)) << 3) + off8);
            af[mt] = fr.s8;
        }
        #pragma unroll
        for (int nt = 0; nt < 4; ++nt) {
            int c = wn * 64 + nt * 16 + l16;
            const short* base = Wsh + c * DD;
            Frag fr;
            fr.u2[0] = *(const uint2*)(base + ((ua       ^ (c & 7)) << 3) + off8);
            fr.u2[1] = *(const uint2*)(base + (((ua + 2) ^ (c & 7)) << 3) + off8);
            bf[nt] = fr.s8;
        }
        #pragma unroll
        for (int mt = 0; mt < 4; ++mt)
            #pragma unroll
            for (int nt = 0; nt < 4; ++nt)
                acc[mt][nt] = __builtin_amdgcn_mfma_f32_16x16x32_bf16(
                                  af[mt], bf[nt], acc[mt][nt], 0, 0, 0);
    }

    // ---- epilogue: rrelu(agg + acc) ----
    #pragma unroll
    for (int mt = 0; mt < 4; ++mt) {
        #pragma unroll
        for (int i = 0; i < 4; ++i) {
            long nrow = n0 + wm * 64 + mt * 16 + 4 * q + i;
            if (nrow < NN) {
                #pragma unroll
                for (int nt = 0; nt < 4; ++nt) {
                    int c = wn * 64 + nt * 16 + l16;
                    float g = __uint_as_float((unsigned)aggb[nrow * DD + c] << 16);
                    float v = g + acc[mt][nt][i];
                    v = (v >= 0.f) ? v : v * SLOPE;
                    if (WRITE_BF16) outb[nrow * DD + c] = (unsigned short)f2bf(v);
                    else            outf[nrow * DD + c] = v;
                }
            }
        }
    }
}

extern "C" void kernel_launch(void* const* d_in, const int* in_sizes, int n_in,
                              void* d_out, int out_size, void* d_ws, size_t ws_size,
                              hipStream_t stream) {
    const float* ent_embeds  = (const float*)d_in[0];
    // d_in[1] = rel_embeds (unused by the layer)
    const float* weight      = (const float*)d_in[2];   // [L, R, 256]
    const float* loop_weight = (const float*)d_in[3];   // [L, 128, 128]
    const float* norm        = (const float*)d_in[4];   // [N, 1]
    const int*   node_id     = (const int*)d_in[5];
    const int*   edge_type   = (const int*)d_in[6];
    const int*   src         = (const int*)d_in[7];
    const int*   dst         = (const int*)d_in[8];
    float*       out         = (float*)d_out;

    // Workspace layout (~58 MB total)
    unsigned short* aggb = (unsigned short*)d_ws;                  // N*D bf16 = 25.6 MB
    unsigned short* hb   = aggb + (size_t)NN * DD;                 // (N+1)*D bf16
    int*   cnt    = (int*)(hb + (size_t)(NN + 1) * DD);            // NN
    int*   off    = cnt + NN;                                      // NN+1
    int*   cursor = off + NN + 1;                                  // NN
    int*   epack  = cursor + NN;                                   // EPMAX (padded)
    int*   bsum   = epack + EPMAX;                                 // 512
    short* wt     = (short*)(bsum + 512);                          // 2*DD*DD bf16 = 64 KB
    unsigned* wb  = (unsigned*)(wt + 2 * DD * DD);                 // 2*RR*128 uints = 235 KB

    const int NB_E = (NE + 255) / 256;
    const int NB_N = (NN + 255) / 256;

    // ---- one-time prep: zero -> fused prep/fill/hist -> scans -> scatter ----
    zero_k  <<<(NN / 4 + 255) / 256, 256, 0, stream>>>(cnt);
    p1_k    <<<P1_TOT, 256, 0, stream>>>(loop_weight, weight, ent_embeds, node_id, dst,
                                         wt, wb, hb, epack, cnt);
    scan1_k <<<NB_N, 256, 0, stream>>>(cnt, off, bsum);
    scan23_k<<<NB_N, 256, 0, stream>>>(off, bsum, cursor, NB_N);
    scat_k  <<<NB_E, 256, 0, stream>>>(src, edge_type, dst, cursor, epack);

    const int AGG_BLOCKS = (NN * 64) / 256;    // one wave per node
    const int APL_BLOCKS = (NN + 127) / 128;   // 128 rows per block

    // ---- layer 0: agg from hb(=h0), apply writes h1 bf16 in-place into hb ----
    agg_k     <<<AGG_BLOCKS, 256, 0, stream>>>(hb, off, epack, wb, norm, aggb);
    apply_k<1><<<APL_BLOCKS, 256, 0, stream>>>(aggb, hb, wt, nullptr, hb);

    // ---- layer 1: agg from hb(=h1), apply writes final f32 out ----
    agg_k     <<<AGG_BLOCKS, 256, 0, stream>>>(hb, off, epack, wb + (size_t)RR * 128,
                                               norm, aggb);
    apply_k<0><<<APL_BLOCKS, 256, 0, stream>>>(aggb, hb, wt + (size_t)DD * DD, out, nullptr);
}